// Round 4
// baseline (357.629 us; speedup 1.0000x reference)
//
#include <hip/hip_runtime.h>

// CoAttention, single fused kernel with MANUAL grid barriers (cooperative API
// failed to launch in R3; this replicates grid.sync with device-scope atomics).
// Co-residency guarantee: __launch_bounds__(256,2) caps VGPR<=256 -> >=2
// blocks/CU; LDS 23KB/block -> 46KB/CU << 160KB; grid 512 = 2*256 CUs, so all
// blocks are resident and the barrier cannot deadlock.
// Stage A: 6 proj GEMMs (E1=exp2(2log2e*(ctx1@Wh1+bh)), E2=exp2(2log2e*ctx2@Wh2),
//          P12,U1,P21,U2) + penalty arrays.       [384 busy blocks, 64x64 tiles]
// Stage B: aff[b,l,m] = sum_k (-2 wo_k)*rcp(E1*E2+1)  (tanh w/ 1 trans/cell),
//          full K per block, writes aff + afft.   [512 tiles 32x32]
// Stage C: row softmax (+col-penalty) -> d12[b][l][m], d21t[b][m][l]. [1 row/wave]
// Stage D: out = tanh(P + dist^T @ U), A already [k][m]-major. [512 tiles 32x32]

#define NEGC (-1e12f)
#define TWO_LOG2E 2.8853900817779268f
#define LOG2E 1.4426950408889634f
#define NBLK 512

union SMem {
    struct { float As[32 * 68]; float Bs[32 * 68]; } a;                       // 17.4 KB
    struct { float E1s[32 * 68]; float E2s[32 * 68]; float affs[32 * 36]; float wos[256]; } b; // 23 KB
    struct { float As[32 * 36]; float Bs[32 * 36]; } d;                       // 9.2 KB
};

__device__ __forceinline__ void gbar(int* cnt)
{
    __syncthreads();
    if (threadIdx.x == 0) {
        __threadfence();                                   // flush block's writes to device scope
        __hip_atomic_fetch_add(cnt, 1, __ATOMIC_RELEASE, __HIP_MEMORY_SCOPE_AGENT);
        while (__hip_atomic_load(cnt, __ATOMIC_ACQUIRE, __HIP_MEMORY_SCOPE_AGENT) < NBLK) {}
        __threadfence();                                   // invalidate stale caches
    }
    __syncthreads();
}

#define CELL(AV, QV, I, J) do {                                       \
    float r0_ = __builtin_amdgcn_rcpf(fmaf(AV.x, QV.x, 1.f));         \
    float r1_ = __builtin_amdgcn_rcpf(fmaf(AV.y, QV.y, 1.f));         \
    float r2_ = __builtin_amdgcn_rcpf(fmaf(AV.z, QV.z, 1.f));         \
    float r3_ = __builtin_amdgcn_rcpf(fmaf(AV.w, QV.w, 1.f));         \
    acc[I][J] = fmaf(w.x, r0_, fmaf(w.y, r1_, fmaf(w.z, r2_,          \
                fmaf(w.w, r3_, acc[I][J]))));                         \
} while (0)

__global__ __launch_bounds__(256, 2) void co_kernel(
    const float* __restrict__ ctx1, const float* __restrict__ ctx2,
    const float* __restrict__ mask1, const float* __restrict__ mask2,
    const float* __restrict__ Wh, const float* __restrict__ bh,
    const float* __restrict__ wo,
    const float* __restrict__ W12, const float* __restrict__ b12,
    const float* __restrict__ W21, const float* __restrict__ b21,
    float* __restrict__ out, float* __restrict__ ws, int* __restrict__ bar)
{
    const int t   = threadIdx.x;
    const int bid = blockIdx.x;
    __shared__ SMem sm;

    float* E1   = ws;                  // [2][512][256]
    float* E2   = E1   + 262144;
    float* P12  = E2   + 262144;       // [2][512(m)][256]
    float* U1   = P12  + 262144;       // [2][512(l)][256]
    float* P21  = U1   + 262144;       // [2][512(l)][256]
    float* U2   = P21  + 262144;       // [2][512(m)][256]
    float* pen1 = U2   + 262144;       // [2][512]
    float* pen2 = pen1 + 1024;
    float* aff  = pen2 + 1024;         // [2][512(l)][512(m)]
    float* afft = aff  + 524288;       // [2][512(m)][512(l)]
    float* d12  = afft + 524288;       // [2][512(l)][512(m)]
    float* d21t = d12  + 524288;       // [2][512(m)][512(l)]

    // ---------------- Stage A: projections --------------------------------
    if (bid < 384) {
        const int g = bid >> 6, rem = bid & 63;
        const int r0 = (rem >> 2) * 64, n0 = (rem & 3) * 64;
        const float* A; const float* W; const float* bias; int expm; float* outp;
        switch (g) {
          case 0:  A = ctx1; W = Wh;         bias = bh;      expm = 1; outp = E1;  break;
          case 1:  A = ctx2; W = Wh + 65536; bias = nullptr; expm = 1; outp = E2;  break;
          case 2:  A = ctx2; W = W12;        bias = b12;     expm = 0; outp = P12; break;
          case 3:  A = ctx1; W = W12 + 65536;bias = nullptr; expm = 0; outp = U1;  break;
          case 4:  A = ctx1; W = W21;        bias = b21;     expm = 0; outp = P21; break;
          default: A = ctx2; W = W21 + 65536;bias = nullptr; expm = 0; outp = U2;  break;
        }
        const int tm4 = (t >> 4) << 2, tn4 = (t & 15) << 2;
        float acc[4][4] = {};
        for (int k0 = 0; k0 < 256; k0 += 32) {
            #pragma unroll
            for (int i = 0; i < 2; ++i) {            // A-tile 64r x 32k, transpose to [k][r]
                int slot = i * 256 + t;
                int r = slot >> 3, kq = (slot & 7) << 2;
                float4 v = *(const float4*)(A + (r0 + r) * 256 + k0 + kq);
                sm.a.As[(kq + 0) * 68 + r] = v.x;
                sm.a.As[(kq + 1) * 68 + r] = v.y;
                sm.a.As[(kq + 2) * 68 + r] = v.z;
                sm.a.As[(kq + 3) * 68 + r] = v.w;
            }
            #pragma unroll
            for (int i = 0; i < 2; ++i) {            // B-tile 32k x 64n straight
                int slot = i * 256 + t;
                int bk = slot >> 4, bn4 = (slot & 15) << 2;
                *(float4*)(sm.a.Bs + bk * 68 + bn4) =
                    *(const float4*)(W + (k0 + bk) * 256 + n0 + bn4);
            }
            __syncthreads();
            #pragma unroll 8
            for (int kk = 0; kk < 32; ++kk) {
                const float4 av = *(const float4*)(sm.a.As + kk * 68 + tm4);
                const float4 bv = *(const float4*)(sm.a.Bs + kk * 68 + tn4);
                acc[0][0] += av.x*bv.x; acc[0][1] += av.x*bv.y; acc[0][2] += av.x*bv.z; acc[0][3] += av.x*bv.w;
                acc[1][0] += av.y*bv.x; acc[1][1] += av.y*bv.y; acc[1][2] += av.y*bv.z; acc[1][3] += av.y*bv.w;
                acc[2][0] += av.z*bv.x; acc[2][1] += av.z*bv.y; acc[2][2] += av.z*bv.z; acc[2][3] += av.z*bv.w;
                acc[3][0] += av.w*bv.x; acc[3][1] += av.w*bv.y; acc[3][2] += av.w*bv.z; acc[3][3] += av.w*bv.w;
            }
            __syncthreads();
        }
        float4 bvz = make_float4(0.f, 0.f, 0.f, 0.f);
        if (bias) bvz = *(const float4*)(bias + n0 + tn4);
        #pragma unroll
        for (int i = 0; i < 4; ++i) {
            int row = r0 + tm4 + i;                  // row = l*2+b
            int orow = ((row & 1) << 9) + (row >> 1);
            float4 v;
            v.x = acc[i][0] + bvz.x; v.y = acc[i][1] + bvz.y;
            v.z = acc[i][2] + bvz.z; v.w = acc[i][3] + bvz.w;
            if (expm) {
                v.x = __builtin_amdgcn_exp2f(v.x * TWO_LOG2E);
                v.y = __builtin_amdgcn_exp2f(v.y * TWO_LOG2E);
                v.z = __builtin_amdgcn_exp2f(v.z * TWO_LOG2E);
                v.w = __builtin_amdgcn_exp2f(v.w * TWO_LOG2E);
            }
            *(float4*)(outp + orow * 256 + n0 + tn4) = v;
        }
    } else if (bid == 384) {
        for (int idx = t; idx < 1024; idx += 256) {
            int row = idx >> 1, b = idx & 1;
            pen1[b * 512 + row] = (1.f - mask1[idx]) * NEGC;
            pen2[b * 512 + row] = (1.f - mask2[idx]) * NEGC;
        }
    }
    gbar(bar + 0);

    // ---------------- Stage B: affinity (trans-bound) ---------------------
    {
        const int b = bid >> 8, rem = bid & 255;
        const int l0 = (rem >> 4) * 32, m0 = (rem & 15) * 32;
        sm.b.wos[t] = -2.f * wo[t];
        const int tl = t >> 4, tm = t & 15;          // cells: l in {tl,tl+16}, m in {tm,tm+16}
        float acc[2][2] = {};
        for (int kc = 0; kc < 256; kc += 64) {
            #pragma unroll
            for (int i = 0; i < 2; ++i) {            // stage 32 rows x 64 k each
                int slot = i * 256 + t;
                int r = slot >> 4, kq = (slot & 15) << 2;
                *(float4*)(sm.b.E1s + r * 68 + kq) =
                    *(const float4*)(E1 + (((b << 9) + l0 + r) << 8) + kc + kq);
                *(float4*)(sm.b.E2s + r * 68 + kq) =
                    *(const float4*)(E2 + (((b << 9) + m0 + r) << 8) + kc + kq);
            }
            __syncthreads();
            #pragma unroll 4
            for (int k0 = 0; k0 < 64; k0 += 4) {
                const float4 w  = *(const float4*)(sm.b.wos + kc + k0);
                const float4 a0 = *(const float4*)(sm.b.E1s + tl * 68 + k0);
                const float4 a1 = *(const float4*)(sm.b.E1s + (tl + 16) * 68 + k0);
                const float4 q0 = *(const float4*)(sm.b.E2s + tm * 68 + k0);
                const float4 q1 = *(const float4*)(sm.b.E2s + (tm + 16) * 68 + k0);
                CELL(a0, q0, 0, 0); CELL(a0, q1, 0, 1);
                CELL(a1, q0, 1, 0); CELL(a1, q1, 1, 1);
            }
            __syncthreads();
        }
        sm.b.affs[tl * 36 + tm]             = acc[0][0];
        sm.b.affs[tl * 36 + tm + 16]        = acc[0][1];
        sm.b.affs[(tl + 16) * 36 + tm]      = acc[1][0];
        sm.b.affs[(tl + 16) * 36 + tm + 16] = acc[1][1];
        __syncthreads();
        const int r = t >> 3, c4 = (t & 7) << 2;
        *(float4*)(aff + (((b << 9) + l0 + r) << 9) + m0 + c4) =
            *(const float4*)(sm.b.affs + r * 36 + c4);
        float4 tv;
        tv.x = sm.b.affs[(c4 + 0) * 36 + r];
        tv.y = sm.b.affs[(c4 + 1) * 36 + r];
        tv.z = sm.b.affs[(c4 + 2) * 36 + r];
        tv.w = sm.b.affs[(c4 + 3) * 36 + r];
        *(float4*)(afft + (((b << 9) + m0 + r) << 9) + l0 + c4) = tv;
    }
    gbar(bar + 1);

    // ---------------- Stage C: dual softmax -------------------------------
    {
        const int rid  = (bid << 2) + (t >> 6);      // 0..2047, one row per wave
        const int lane = t & 63;
        const bool second = rid >= 1024;
        const int rr = rid & 1023;
        const int b  = rr >> 9;
        const float* base = (second ? afft : aff) + rr * 512;
        const float* pen  = (second ? pen1 : pen2) + (b << 9);
        float* dst = (second ? d21t : d12) + rr * 512;
        const int c = lane << 2;
        float4 v0 = *(const float4*)(base + c);
        float4 v1 = *(const float4*)(base + 256 + c);
        float4 p0 = *(const float4*)(pen + c);
        float4 p1 = *(const float4*)(pen + 256 + c);
        v0.x += p0.x; v0.y += p0.y; v0.z += p0.z; v0.w += p0.w;
        v1.x += p1.x; v1.y += p1.y; v1.z += p1.z; v1.w += p1.w;
        float mx = fmaxf(fmaxf(fmaxf(v0.x, v0.y), fmaxf(v0.z, v0.w)),
                         fmaxf(fmaxf(v1.x, v1.y), fmaxf(v1.z, v1.w)));
        #pragma unroll
        for (int off = 1; off < 64; off <<= 1)
            mx = fmaxf(mx, __shfl_xor(mx, off, 64));
        float e0 = __builtin_amdgcn_exp2f((v0.x - mx) * LOG2E);
        float e1 = __builtin_amdgcn_exp2f((v0.y - mx) * LOG2E);
        float e2 = __builtin_amdgcn_exp2f((v0.z - mx) * LOG2E);
        float e3 = __builtin_amdgcn_exp2f((v0.w - mx) * LOG2E);
        float e4 = __builtin_amdgcn_exp2f((v1.x - mx) * LOG2E);
        float e5 = __builtin_amdgcn_exp2f((v1.y - mx) * LOG2E);
        float e6 = __builtin_amdgcn_exp2f((v1.z - mx) * LOG2E);
        float e7 = __builtin_amdgcn_exp2f((v1.w - mx) * LOG2E);
        float sum = ((e0 + e1) + (e2 + e3)) + ((e4 + e5) + (e6 + e7));
        #pragma unroll
        for (int off = 1; off < 64; off <<= 1)
            sum += __shfl_xor(sum, off, 64);
        const float inv = __builtin_amdgcn_rcpf(sum);
        *(float4*)(dst + c)       = make_float4(e0 * inv, e1 * inv, e2 * inv, e3 * inv);
        *(float4*)(dst + 256 + c) = make_float4(e4 * inv, e5 * inv, e6 * inv, e7 * inv);
    }
    gbar(bar + 2);

    // ---------------- Stage D: final GEMMs + tanh -------------------------
    {
        const int dir = bid >> 8, rem = bid & 255;
        const int b = rem >> 7, rem2 = rem & 127;
        const int r0 = (rem2 >> 3) * 32, n0 = (rem2 & 7) * 32;
        const float* Ag = (dir == 0 ? d12 : d21t) + b * 262144;  // [k 512][row 512]
        const float* Bg = (dir == 0 ? U1  : U2)   + b * 131072;  // [k 512][n 256]
        const float* Pg = (dir == 0 ? P12 : P21)  + b * 131072;  // [row 512][n 256]
        float* o = out + (dir == 0 ? 262144 : 0);
        const int tm_ = t >> 4, tn_ = t & 15;        // cells: row r0+2tm_+i, col n0+2tn_+j
        float acc[2][2] = {};
        for (int k0 = 0; k0 < 512; k0 += 32) {
            const int r = t >> 3, c4 = (t & 7) << 2;
            *(float4*)(sm.d.As + r * 36 + c4) =
                *(const float4*)(Ag + ((k0 + r) << 9) + r0 + c4);
            *(float4*)(sm.d.Bs + r * 36 + c4) =
                *(const float4*)(Bg + ((k0 + r) << 8) + n0 + c4);
            __syncthreads();
            #pragma unroll 8
            for (int kk = 0; kk < 32; ++kk) {
                const float2 av = *(const float2*)(sm.d.As + kk * 36 + tm_ * 2);
                const float2 bv = *(const float2*)(sm.d.Bs + kk * 36 + tn_ * 2);
                acc[0][0] += av.x * bv.x; acc[0][1] += av.x * bv.y;
                acc[1][0] += av.y * bv.x; acc[1][1] += av.y * bv.y;
            }
            __syncthreads();
        }
        #pragma unroll
        for (int i = 0; i < 2; ++i) {
            const int m = r0 + tm_ * 2 + i;
            float2 p = *(const float2*)(Pg + (m << 8) + n0 + tn_ * 2);
            float vx = acc[i][0] + p.x;
            float vy = acc[i][1] + p.y;
            float tx = 1.f - 2.f * __builtin_amdgcn_rcpf(
                           __builtin_amdgcn_exp2f(vx * TWO_LOG2E) + 1.f);
            float ty = 1.f - 2.f * __builtin_amdgcn_rcpf(
                           __builtin_amdgcn_exp2f(vy * TWO_LOG2E) + 1.f);
            *(float2*)(o + ((m << 1) + b) * 256 + n0 + tn_ * 2) = make_float2(tx, ty);
        }
    }
}

extern "C" void kernel_launch(void* const* d_in, const int* in_sizes, int n_in,
                              void* d_out, int out_size, void* d_ws, size_t ws_size,
                              hipStream_t stream)
{
    const float* ctx1 = (const float*)d_in[0];
    const float* ctx2 = (const float*)d_in[1];
    const float* m1   = (const float*)d_in[2];
    const float* m2   = (const float*)d_in[3];
    const float* Wh   = (const float*)d_in[4];
    const float* bh   = (const float*)d_in[5];
    const float* wo   = (const float*)d_in[6];
    const float* W12  = (const float*)d_in[7];
    const float* b12  = (const float*)d_in[8];
    const float* W21  = (const float*)d_in[9];
    const float* b21  = (const float*)d_in[10];
    float* out = (float*)d_out;
    float* ws  = (float*)d_ws;

    // barrier counters after the 3,672,064 floats of tensor workspace
    int* bar = (int*)(ws + 3672064);
    hipMemsetAsync((void*)bar, 0, 4 * sizeof(int), stream);  // graph-legal memset node

    hipLaunchKernelGGL(co_kernel, dim3(NBLK), dim3(256), 0, stream,
                       ctx1, ctx2, m1, m2, Wh, bh, wo,
                       W12, b12, W21, b21, out, ws, bar);
}

// Round 5
// 258.483 us; speedup vs baseline: 1.3836x; 1.3836x over previous
//
#include <hip/hip_runtime.h>

// CoAttention, single fused kernel with manual grid barriers.
// R5 change (ONLY change vs R4): gbar() rewritten — R4 spun on an AGENT-scope
// ACQUIRE atomic load, which emits a cache-invalidate per poll iteration;
// 512 blocks polling = continuous L2-invalidate storm (~80us/barrier, 8.5%
// VALUBusy). Now: one RELEASE fence before the relaxed add, RELAXED polling
// (agent-scope load reads through to coherence point without invalidating),
// s_sleep backoff, one ACQUIRE fence after exit.
// Co-residency: __launch_bounds__(256,2) -> >=2 blocks/CU; LDS 23KB; grid 512
// = 2*256 CUs, so all blocks resident; barrier cannot deadlock.

#define NEGC (-1e12f)
#define TWO_LOG2E 2.8853900817779268f
#define LOG2E 1.4426950408889634f
#define NBLK 512

union SMem {
    struct { float As[32 * 68]; float Bs[32 * 68]; } a;                       // 17.4 KB
    struct { float E1s[32 * 68]; float E2s[32 * 68]; float affs[32 * 36]; float wos[256]; } b; // 23 KB
    struct { float As[32 * 36]; float Bs[32 * 36]; } d;                       // 9.2 KB
};

__device__ __forceinline__ void gbar(int* cnt)
{
    __syncthreads();
    if (threadIdx.x == 0) {
        __builtin_amdgcn_fence(__ATOMIC_RELEASE, "agent");   // one wbl2
        __hip_atomic_fetch_add(cnt, 1, __ATOMIC_RELAXED, __HIP_MEMORY_SCOPE_AGENT);
        while (__hip_atomic_load(cnt, __ATOMIC_RELAXED, __HIP_MEMORY_SCOPE_AGENT) < NBLK)
            __builtin_amdgcn_s_sleep(16);                    // ~1k-cycle backoff
        __builtin_amdgcn_fence(__ATOMIC_ACQUIRE, "agent");   // one buffer_inv
    }
    __syncthreads();
}

#define CELL(AV, QV, I, J) do {                                       \
    float r0_ = __builtin_amdgcn_rcpf(fmaf(AV.x, QV.x, 1.f));         \
    float r1_ = __builtin_amdgcn_rcpf(fmaf(AV.y, QV.y, 1.f));         \
    float r2_ = __builtin_amdgcn_rcpf(fmaf(AV.z, QV.z, 1.f));         \
    float r3_ = __builtin_amdgcn_rcpf(fmaf(AV.w, QV.w, 1.f));         \
    acc[I][J] = fmaf(w.x, r0_, fmaf(w.y, r1_, fmaf(w.z, r2_,          \
                fmaf(w.w, r3_, acc[I][J]))));                         \
} while (0)

__global__ __launch_bounds__(256, 2) void co_kernel(
    const float* __restrict__ ctx1, const float* __restrict__ ctx2,
    const float* __restrict__ mask1, const float* __restrict__ mask2,
    const float* __restrict__ Wh, const float* __restrict__ bh,
    const float* __restrict__ wo,
    const float* __restrict__ W12, const float* __restrict__ b12,
    const float* __restrict__ W21, const float* __restrict__ b21,
    float* __restrict__ out, float* __restrict__ ws, int* __restrict__ bar)
{
    const int t   = threadIdx.x;
    const int bid = blockIdx.x;
    __shared__ SMem sm;

    float* E1   = ws;                  // [2][512][256]
    float* E2   = E1   + 262144;
    float* P12  = E2   + 262144;       // [2][512(m)][256]
    float* U1   = P12  + 262144;       // [2][512(l)][256]
    float* P21  = U1   + 262144;       // [2][512(l)][256]
    float* U2   = P21  + 262144;       // [2][512(m)][256]
    float* pen1 = U2   + 262144;       // [2][512]
    float* pen2 = pen1 + 1024;
    float* aff  = pen2 + 1024;         // [2][512(l)][512(m)]
    float* afft = aff  + 524288;       // [2][512(m)][512(l)]
    float* d12  = afft + 524288;       // [2][512(l)][512(m)]
    float* d21t = d12  + 524288;       // [2][512(m)][512(l)]

    // ---------------- Stage A: projections --------------------------------
    if (bid < 384) {
        const int g = bid >> 6, rem = bid & 63;
        const int r0 = (rem >> 2) * 64, n0 = (rem & 3) * 64;
        const float* A; const float* W; const float* bias; int expm; float* outp;
        switch (g) {
          case 0:  A = ctx1; W = Wh;         bias = bh;      expm = 1; outp = E1;  break;
          case 1:  A = ctx2; W = Wh + 65536; bias = nullptr; expm = 1; outp = E2;  break;
          case 2:  A = ctx2; W = W12;        bias = b12;     expm = 0; outp = P12; break;
          case 3:  A = ctx1; W = W12 + 65536;bias = nullptr; expm = 0; outp = U1;  break;
          case 4:  A = ctx1; W = W21;        bias = b21;     expm = 0; outp = P21; break;
          default: A = ctx2; W = W21 + 65536;bias = nullptr; expm = 0; outp = U2;  break;
        }
        const int tm4 = (t >> 4) << 2, tn4 = (t & 15) << 2;
        float acc[4][4] = {};
        for (int k0 = 0; k0 < 256; k0 += 32) {
            #pragma unroll
            for (int i = 0; i < 2; ++i) {            // A-tile 64r x 32k, transpose to [k][r]
                int slot = i * 256 + t;
                int r = slot >> 3, kq = (slot & 7) << 2;
                float4 v = *(const float4*)(A + (r0 + r) * 256 + k0 + kq);
                sm.a.As[(kq + 0) * 68 + r] = v.x;
                sm.a.As[(kq + 1) * 68 + r] = v.y;
                sm.a.As[(kq + 2) * 68 + r] = v.z;
                sm.a.As[(kq + 3) * 68 + r] = v.w;
            }
            #pragma unroll
            for (int i = 0; i < 2; ++i) {            // B-tile 32k x 64n straight
                int slot = i * 256 + t;
                int bk = slot >> 4, bn4 = (slot & 15) << 2;
                *(float4*)(sm.a.Bs + bk * 68 + bn4) =
                    *(const float4*)(W + (k0 + bk) * 256 + n0 + bn4);
            }
            __syncthreads();
            #pragma unroll 8
            for (int kk = 0; kk < 32; ++kk) {
                const float4 av = *(const float4*)(sm.a.As + kk * 68 + tm4);
                const float4 bv = *(const float4*)(sm.a.Bs + kk * 68 + tn4);
                acc[0][0] += av.x*bv.x; acc[0][1] += av.x*bv.y; acc[0][2] += av.x*bv.z; acc[0][3] += av.x*bv.w;
                acc[1][0] += av.y*bv.x; acc[1][1] += av.y*bv.y; acc[1][2] += av.y*bv.z; acc[1][3] += av.y*bv.w;
                acc[2][0] += av.z*bv.x; acc[2][1] += av.z*bv.y; acc[2][2] += av.z*bv.z; acc[2][3] += av.z*bv.w;
                acc[3][0] += av.w*bv.x; acc[3][1] += av.w*bv.y; acc[3][2] += av.w*bv.z; acc[3][3] += av.w*bv.w;
            }
            __syncthreads();
        }
        float4 bvz = make_float4(0.f, 0.f, 0.f, 0.f);
        if (bias) bvz = *(const float4*)(bias + n0 + tn4);
        #pragma unroll
        for (int i = 0; i < 4; ++i) {
            int row = r0 + tm4 + i;                  // row = l*2+b
            int orow = ((row & 1) << 9) + (row >> 1);
            float4 v;
            v.x = acc[i][0] + bvz.x; v.y = acc[i][1] + bvz.y;
            v.z = acc[i][2] + bvz.z; v.w = acc[i][3] + bvz.w;
            if (expm) {
                v.x = __builtin_amdgcn_exp2f(v.x * TWO_LOG2E);
                v.y = __builtin_amdgcn_exp2f(v.y * TWO_LOG2E);
                v.z = __builtin_amdgcn_exp2f(v.z * TWO_LOG2E);
                v.w = __builtin_amdgcn_exp2f(v.w * TWO_LOG2E);
            }
            *(float4*)(outp + orow * 256 + n0 + tn4) = v;
        }
    } else if (bid == 384) {
        for (int idx = t; idx < 1024; idx += 256) {
            int row = idx >> 1, b = idx & 1;
            pen1[b * 512 + row] = (1.f - mask1[idx]) * NEGC;
            pen2[b * 512 + row] = (1.f - mask2[idx]) * NEGC;
        }
    }
    gbar(bar + 0);

    // ---------------- Stage B: affinity (trans-bound) ---------------------
    {
        const int b = bid >> 8, rem = bid & 255;
        const int l0 = (rem >> 4) * 32, m0 = (rem & 15) * 32;
        sm.b.wos[t] = -2.f * wo[t];
        const int tl = t >> 4, tm = t & 15;          // cells: l in {tl,tl+16}, m in {tm,tm+16}
        float acc[2][2] = {};
        for (int kc = 0; kc < 256; kc += 64) {
            #pragma unroll
            for (int i = 0; i < 2; ++i) {            // stage 32 rows x 64 k each
                int slot = i * 256 + t;
                int r = slot >> 4, kq = (slot & 15) << 2;
                *(float4*)(sm.b.E1s + r * 68 + kq) =
                    *(const float4*)(E1 + (((b << 9) + l0 + r) << 8) + kc + kq);
                *(float4*)(sm.b.E2s + r * 68 + kq) =
                    *(const float4*)(E2 + (((b << 9) + m0 + r) << 8) + kc + kq);
            }
            __syncthreads();
            #pragma unroll 4
            for (int k0 = 0; k0 < 64; k0 += 4) {
                const float4 w  = *(const float4*)(sm.b.wos + kc + k0);
                const float4 a0 = *(const float4*)(sm.b.E1s + tl * 68 + k0);
                const float4 a1 = *(const float4*)(sm.b.E1s + (tl + 16) * 68 + k0);
                const float4 q0 = *(const float4*)(sm.b.E2s + tm * 68 + k0);
                const float4 q1 = *(const float4*)(sm.b.E2s + (tm + 16) * 68 + k0);
                CELL(a0, q0, 0, 0); CELL(a0, q1, 0, 1);
                CELL(a1, q0, 1, 0); CELL(a1, q1, 1, 1);
            }
            __syncthreads();
        }
        sm.b.affs[tl * 36 + tm]             = acc[0][0];
        sm.b.affs[tl * 36 + tm + 16]        = acc[0][1];
        sm.b.affs[(tl + 16) * 36 + tm]      = acc[1][0];
        sm.b.affs[(tl + 16) * 36 + tm + 16] = acc[1][1];
        __syncthreads();
        const int r = t >> 3, c4 = (t & 7) << 2;
        *(float4*)(aff + (((b << 9) + l0 + r) << 9) + m0 + c4) =
            *(const float4*)(sm.b.affs + r * 36 + c4);
        float4 tv;
        tv.x = sm.b.affs[(c4 + 0) * 36 + r];
        tv.y = sm.b.affs[(c4 + 1) * 36 + r];
        tv.z = sm.b.affs[(c4 + 2) * 36 + r];
        tv.w = sm.b.affs[(c4 + 3) * 36 + r];
        *(float4*)(afft + (((b << 9) + m0 + r) << 9) + l0 + c4) = tv;
    }
    gbar(bar + 1);

    // ---------------- Stage C: dual softmax -------------------------------
    {
        const int rid  = (bid << 2) + (t >> 6);      // 0..2047, one row per wave
        const int lane = t & 63;
        const bool second = rid >= 1024;
        const int rr = rid & 1023;
        const int b  = rr >> 9;
        const float* base = (second ? afft : aff) + rr * 512;
        const float* pen  = (second ? pen1 : pen2) + (b << 9);
        float* dst = (second ? d21t : d12) + rr * 512;
        const int c = lane << 2;
        float4 v0 = *(const float4*)(base + c);
        float4 v1 = *(const float4*)(base + 256 + c);
        float4 p0 = *(const float4*)(pen + c);
        float4 p1 = *(const float4*)(pen + 256 + c);
        v0.x += p0.x; v0.y += p0.y; v0.z += p0.z; v0.w += p0.w;
        v1.x += p1.x; v1.y += p1.y; v1.z += p1.z; v1.w += p1.w;
        float mx = fmaxf(fmaxf(fmaxf(v0.x, v0.y), fmaxf(v0.z, v0.w)),
                         fmaxf(fmaxf(v1.x, v1.y), fmaxf(v1.z, v1.w)));
        #pragma unroll
        for (int off = 1; off < 64; off <<= 1)
            mx = fmaxf(mx, __shfl_xor(mx, off, 64));
        float e0 = __builtin_amdgcn_exp2f((v0.x - mx) * LOG2E);
        float e1 = __builtin_amdgcn_exp2f((v0.y - mx) * LOG2E);
        float e2 = __builtin_amdgcn_exp2f((v0.z - mx) * LOG2E);
        float e3 = __builtin_amdgcn_exp2f((v0.w - mx) * LOG2E);
        float e4 = __builtin_amdgcn_exp2f((v1.x - mx) * LOG2E);
        float e5 = __builtin_amdgcn_exp2f((v1.y - mx) * LOG2E);
        float e6 = __builtin_amdgcn_exp2f((v1.z - mx) * LOG2E);
        float e7 = __builtin_amdgcn_exp2f((v1.w - mx) * LOG2E);
        float sum = ((e0 + e1) + (e2 + e3)) + ((e4 + e5) + (e6 + e7));
        #pragma unroll
        for (int off = 1; off < 64; off <<= 1)
            sum += __shfl_xor(sum, off, 64);
        const float inv = __builtin_amdgcn_rcpf(sum);
        *(float4*)(dst + c)       = make_float4(e0 * inv, e1 * inv, e2 * inv, e3 * inv);
        *(float4*)(dst + 256 + c) = make_float4(e4 * inv, e5 * inv, e6 * inv, e7 * inv);
    }
    gbar(bar + 2);

    // ---------------- Stage D: final GEMMs + tanh -------------------------
    {
        const int dir = bid >> 8, rem = bid & 255;
        const int b = rem >> 7, rem2 = rem & 127;
        const int r0 = (rem2 >> 3) * 32, n0 = (rem2 & 7) * 32;
        const float* Ag = (dir == 0 ? d12 : d21t) + b * 262144;  // [k 512][row 512]
        const float* Bg = (dir == 0 ? U1  : U2)   + b * 131072;  // [k 512][n 256]
        const float* Pg = (dir == 0 ? P12 : P21)  + b * 131072;  // [row 512][n 256]
        float* o = out + (dir == 0 ? 262144 : 0);
        const int tm_ = t >> 4, tn_ = t & 15;        // cells: row r0+2tm_+i, col n0+2tn_+j
        float acc[2][2] = {};
        for (int k0 = 0; k0 < 512; k0 += 32) {
            const int r = t >> 3, c4 = (t & 7) << 2;
            *(float4*)(sm.d.As + r * 36 + c4) =
                *(const float4*)(Ag + ((k0 + r) << 9) + r0 + c4);
            *(float4*)(sm.d.Bs + r * 36 + c4) =
                *(const float4*)(Bg + ((k0 + r) << 8) + n0 + c4);
            __syncthreads();
            #pragma unroll 8
            for (int kk = 0; kk < 32; ++kk) {
                const float2 av = *(const float2*)(sm.d.As + kk * 36 + tm_ * 2);
                const float2 bv = *(const float2*)(sm.d.Bs + kk * 36 + tn_ * 2);
                acc[0][0] += av.x * bv.x; acc[0][1] += av.x * bv.y;
                acc[1][0] += av.y * bv.x; acc[1][1] += av.y * bv.y;
            }
            __syncthreads();
        }
        #pragma unroll
        for (int i = 0; i < 2; ++i) {
            const int m = r0 + tm_ * 2 + i;
            float2 p = *(const float2*)(Pg + (m << 8) + n0 + tn_ * 2);
            float vx = acc[i][0] + p.x;
            float vy = acc[i][1] + p.y;
            float tx = 1.f - 2.f * __builtin_amdgcn_rcpf(
                           __builtin_amdgcn_exp2f(vx * TWO_LOG2E) + 1.f);
            float ty = 1.f - 2.f * __builtin_amdgcn_rcpf(
                           __builtin_amdgcn_exp2f(vy * TWO_LOG2E) + 1.f);
            *(float2*)(o + ((m << 1) + b) * 256 + n0 + tn_ * 2) = make_float2(tx, ty);
        }
    }
}

extern "C" void kernel_launch(void* const* d_in, const int* in_sizes, int n_in,
                              void* d_out, int out_size, void* d_ws, size_t ws_size,
                              hipStream_t stream)
{
    const float* ctx1 = (const float*)d_in[0];
    const float* ctx2 = (const float*)d_in[1];
    const float* m1   = (const float*)d_in[2];
    const float* m2   = (const float*)d_in[3];
    const float* Wh   = (const float*)d_in[4];
    const float* bh   = (const float*)d_in[5];
    const float* wo   = (const float*)d_in[6];
    const float* W12  = (const float*)d_in[7];
    const float* b12  = (const float*)d_in[8];
    const float* W21  = (const float*)d_in[9];
    const float* b21  = (const float*)d_in[10];
    float* out = (float*)d_out;
    float* ws  = (float*)d_ws;

    // barrier counters after the 3,672,064 floats of tensor workspace
    int* bar = (int*)(ws + 3672064);
    hipMemsetAsync((void*)bar, 0, 4 * sizeof(int), stream);  // graph-legal memset node

    hipLaunchKernelGGL(co_kernel, dim3(NBLK), dim3(256), 0, stream,
                       ctx1, ctx2, m1, m2, Wh, bh, wo,
                       W12, b12, W21, b21, out, ws, bar);
}

// Round 6
// 149.480 us; speedup vs baseline: 2.3925x; 1.7292x over previous
//
#include <hip/hip_runtime.h>

// CoAttention, 3-kernel pipeline (grid barriers abandoned: R4/R5 showed each
// manual barrier costs ~45-100us; harness also has a fixed ~64us poison-fill
// inside the timed region, so dispatch count only costs small graph gaps).
//  k_proj : 6 batched GEMMs 1024x256x256: E1=exp2(2log2e*(ctx1@Wh1+bh)),
//           E2=exp2(2log2e*ctx2@Wh2), P12,U1,P21,U2. Aux block: mask
//           multipliers p1/p2 = exp(pen) in {0,1}, zero S1/S2.
//  k_aff  : per 32x32 tile: acc = sum_k (-2wo_k)*rcp(E1*E2+1)  (= aff - SW,
//           SW constant cancels in both softmaxes); E = exp2(acc*log2e)
//           (no max-subtraction: |acc| <= ~20, fp32-safe);
//           writes ER[l][m]=E*p2[m], ECT[m][l]=E*p1[l];
//           atomicAdd S1[l]=sum_m ER, S2[m]=sum_l E*p1.
//  k_final: out12 = tanh(P12 + (ER*rcp(S1[l]))^T-contraction @ U1)  (d12=ER/S1)
//           out21 = tanh(P21 + (ECT*rcp(S2[m])) @ U2)               (d21=E*p1/S2)
//           normalization folded into A-tile staging (scale by contraction idx).

#define NEGC (-1e12f)
#define TWO_LOG2E 2.8853900817779268f
#define LOG2E 1.4426950408889634f

// ---------------------------------------------------------------- k_proj
__global__ __launch_bounds__(256) void k_proj(
    const float* __restrict__ ctx1, const float* __restrict__ ctx2,
    const float* __restrict__ Wh, const float* __restrict__ bh,
    const float* __restrict__ W12, const float* __restrict__ b12,
    const float* __restrict__ W21, const float* __restrict__ b21,
    const float* __restrict__ mask1, const float* __restrict__ mask2,
    float* __restrict__ E1, float* __restrict__ E2,
    float* __restrict__ P12, float* __restrict__ U1,
    float* __restrict__ P21, float* __restrict__ U2,
    float* __restrict__ p1, float* __restrict__ p2,
    float* __restrict__ S1, float* __restrict__ S2)
{
    const int t  = threadIdx.x;
    const int g  = blockIdx.z;
    const int r0 = blockIdx.x * 64;       // rows = l*2+b in [0,1024)
    const int n0 = blockIdx.y * 64;       // N in [0,256)

    const float* A; const float* W; const float* bias; int expm; float* outp;
    switch (g) {
      case 0:  A=ctx1; W=Wh;        bias=bh;   expm=1; outp=E1;  break;
      case 1:  A=ctx2; W=Wh+65536;  bias=0;    expm=1; outp=E2;  break;
      case 2:  A=ctx2; W=W12;       bias=b12;  expm=0; outp=P12; break;
      case 3:  A=ctx1; W=W12+65536; bias=0;    expm=0; outp=U1;  break;
      case 4:  A=ctx1; W=W21;       bias=b21;  expm=0; outp=P21; break;
      default: A=ctx2; W=W21+65536; bias=0;    expm=0; outp=U2;  break;
    }

    if (g == 0 && blockIdx.x == 0 && blockIdx.y == 0) {
        for (int idx = t; idx < 1024; idx += 256) {
            int row = idx >> 1, b = idx & 1;
            p1[b * 512 + row] = __builtin_amdgcn_exp2f(LOG2E * (1.f - mask1[idx]) * NEGC);
            p2[b * 512 + row] = __builtin_amdgcn_exp2f(LOG2E * (1.f - mask2[idx]) * NEGC);
            S1[b * 512 + row] = 0.f;
            S2[b * 512 + row] = 0.f;
        }
    }

    __shared__ __align__(16) float As[32 * 68];   // [k][m]
    __shared__ __align__(16) float Bs[32 * 68];   // [k][n]
    const int tm4 = (t >> 4) << 2;
    const int tn4 = (t & 15) << 2;
    float acc[4][4] = {};

    for (int k0 = 0; k0 < 256; k0 += 32) {
        #pragma unroll
        for (int i = 0; i < 2; ++i) {            // A: 64 rows x 32 k -> transpose
            int slot = i * 256 + t;
            int r = slot >> 3, kq = (slot & 7) << 2;
            float4 v = *(const float4*)(A + (r0 + r) * 256 + k0 + kq);
            As[(kq + 0) * 68 + r] = v.x;
            As[(kq + 1) * 68 + r] = v.y;
            As[(kq + 2) * 68 + r] = v.z;
            As[(kq + 3) * 68 + r] = v.w;
        }
        #pragma unroll
        for (int i = 0; i < 2; ++i) {            // B: 32 k x 64 n straight
            int slot = i * 256 + t;
            int bk = slot >> 4, bn4 = (slot & 15) << 2;
            *(float4*)(Bs + bk * 68 + bn4) =
                *(const float4*)(W + (k0 + bk) * 256 + n0 + bn4);
        }
        __syncthreads();
        #pragma unroll 8
        for (int kk = 0; kk < 32; ++kk) {
            const float4 av = *(const float4*)(As + kk * 68 + tm4);
            const float4 bv = *(const float4*)(Bs + kk * 68 + tn4);
            acc[0][0] += av.x*bv.x; acc[0][1] += av.x*bv.y; acc[0][2] += av.x*bv.z; acc[0][3] += av.x*bv.w;
            acc[1][0] += av.y*bv.x; acc[1][1] += av.y*bv.y; acc[1][2] += av.y*bv.z; acc[1][3] += av.y*bv.w;
            acc[2][0] += av.z*bv.x; acc[2][1] += av.z*bv.y; acc[2][2] += av.z*bv.z; acc[2][3] += av.z*bv.w;
            acc[3][0] += av.w*bv.x; acc[3][1] += av.w*bv.y; acc[3][2] += av.w*bv.z; acc[3][3] += av.w*bv.w;
        }
        __syncthreads();
    }

    float4 bvz = make_float4(0.f, 0.f, 0.f, 0.f);
    if (bias) bvz = *(const float4*)(bias + n0 + tn4);
    #pragma unroll
    for (int i = 0; i < 4; ++i) {
        int row = r0 + tm4 + i;                  // row = l*2+b
        int orow = ((row & 1) << 9) + (row >> 1);
        float4 v;
        v.x = acc[i][0] + bvz.x; v.y = acc[i][1] + bvz.y;
        v.z = acc[i][2] + bvz.z; v.w = acc[i][3] + bvz.w;
        if (expm) {
            v.x = __builtin_amdgcn_exp2f(v.x * TWO_LOG2E);
            v.y = __builtin_amdgcn_exp2f(v.y * TWO_LOG2E);
            v.z = __builtin_amdgcn_exp2f(v.z * TWO_LOG2E);
            v.w = __builtin_amdgcn_exp2f(v.w * TWO_LOG2E);
        }
        *(float4*)(outp + orow * 256 + n0 + tn4) = v;
    }
}

// ---------------------------------------------------------------- k_aff
#define CELL(AV, QV, I, J) do {                                       \
    float r0_ = __builtin_amdgcn_rcpf(fmaf(AV.x, QV.x, 1.f));         \
    float r1_ = __builtin_amdgcn_rcpf(fmaf(AV.y, QV.y, 1.f));         \
    float r2_ = __builtin_amdgcn_rcpf(fmaf(AV.z, QV.z, 1.f));         \
    float r3_ = __builtin_amdgcn_rcpf(fmaf(AV.w, QV.w, 1.f));         \
    acc[I][J] = fmaf(w.x, r0_, fmaf(w.y, r1_, fmaf(w.z, r2_,          \
                fmaf(w.w, r3_, acc[I][J]))));                         \
} while (0)

__global__ __launch_bounds__(256, 2) void k_aff(
    const float* __restrict__ E1g, const float* __restrict__ E2g,
    const float* __restrict__ wo,
    const float* __restrict__ p1g, const float* __restrict__ p2g,
    float* __restrict__ ER, float* __restrict__ ECT,
    float* __restrict__ S1, float* __restrict__ S2)
{
    const int t  = threadIdx.x;
    const int l0 = blockIdx.x * 32, m0 = blockIdx.y * 32, b = blockIdx.z;

    __shared__ __align__(16) float E1s[32 * 68];
    __shared__ __align__(16) float E2s[32 * 68];
    __shared__ __align__(16) float wos[256];
    __shared__ __align__(16) float affs[32 * 36];

    wos[t] = -2.f * wo[t];
    const int tl = t >> 4, tm = t & 15;
    float acc[2][2] = {};

    for (int kc = 0; kc < 256; kc += 64) {
        #pragma unroll
        for (int i = 0; i < 2; ++i) {
            int slot = i * 256 + t;
            int r = slot >> 4, kq = (slot & 15) << 2;
            *(float4*)(E1s + r * 68 + kq) =
                *(const float4*)(E1g + (((b << 9) + l0 + r) << 8) + kc + kq);
            *(float4*)(E2s + r * 68 + kq) =
                *(const float4*)(E2g + (((b << 9) + m0 + r) << 8) + kc + kq);
        }
        __syncthreads();
        #pragma unroll 4
        for (int k0 = 0; k0 < 64; k0 += 4) {
            const float4 w  = *(const float4*)(wos + kc + k0);
            const float4 a0 = *(const float4*)(E1s + tl * 68 + k0);
            const float4 a1 = *(const float4*)(E1s + (tl + 16) * 68 + k0);
            const float4 q0 = *(const float4*)(E2s + tm * 68 + k0);
            const float4 q1 = *(const float4*)(E2s + (tm + 16) * 68 + k0);
            CELL(a0, q0, 0, 0); CELL(a0, q1, 0, 1);
            CELL(a1, q0, 1, 0); CELL(a1, q1, 1, 1);
        }
        __syncthreads();
    }

    // E = exp(aff - SW); SW constant cancels in both softmaxes
    affs[tl * 36 + tm]               = __builtin_amdgcn_exp2f(acc[0][0] * LOG2E);
    affs[tl * 36 + tm + 16]          = __builtin_amdgcn_exp2f(acc[0][1] * LOG2E);
    affs[(tl + 16) * 36 + tm]        = __builtin_amdgcn_exp2f(acc[1][0] * LOG2E);
    affs[(tl + 16) * 36 + tm + 16]   = __builtin_amdgcn_exp2f(acc[1][1] * LOG2E);
    __syncthreads();

    const int r = t >> 3, c4 = (t & 7) << 2;
    // ER[l][m] = E * p2[m]; S1[l] += row sums
    {
        float4 e   = *(const float4*)(affs + r * 36 + c4);
        float4 p2v = *(const float4*)(p2g + (b << 9) + m0 + c4);
        float4 v = make_float4(e.x * p2v.x, e.y * p2v.y, e.z * p2v.z, e.w * p2v.w);
        *(float4*)(ER + (((b << 9) + l0 + r) << 9) + m0 + c4) = v;
        float s = (v.x + v.y) + (v.z + v.w);
        s += __shfl_xor(s, 1, 64);
        s += __shfl_xor(s, 2, 64);
        s += __shfl_xor(s, 4, 64);
        if ((t & 7) == 0) atomicAdd(S1 + (b << 9) + l0 + r, s);
    }
    // ECT[m][l] = E[l][m] * p1[l]; S2[m] += col sums
    {
        float4 p1v = *(const float4*)(p1g + (b << 9) + l0 + c4);
        float4 tv;
        tv.x = affs[(c4 + 0) * 36 + r] * p1v.x;
        tv.y = affs[(c4 + 1) * 36 + r] * p1v.y;
        tv.z = affs[(c4 + 2) * 36 + r] * p1v.z;
        tv.w = affs[(c4 + 3) * 36 + r] * p1v.w;
        *(float4*)(ECT + (((b << 9) + m0 + r) << 9) + l0 + c4) = tv;
        float s = (tv.x + tv.y) + (tv.z + tv.w);
        s += __shfl_xor(s, 1, 64);
        s += __shfl_xor(s, 2, 64);
        s += __shfl_xor(s, 4, 64);
        if ((t & 7) == 0) atomicAdd(S2 + (b << 9) + m0 + r, s);
    }
}

// --------------------------------------------------------------- k_final
__global__ __launch_bounds__(256) void k_final(
    const float* __restrict__ ER, const float* __restrict__ ECT,
    const float* __restrict__ U1, const float* __restrict__ U2,
    const float* __restrict__ P12, const float* __restrict__ P21,
    const float* __restrict__ S1, const float* __restrict__ S2,
    float* __restrict__ out)
{
    const int t   = threadIdx.x;
    const int r0  = blockIdx.x * 64, n0 = blockIdx.y * 32;
    const int dir = blockIdx.z >> 1, b = blockIdx.z & 1;
    const float* Ag = (dir == 0 ? ER  : ECT) + b * 262144;  // [k][row], stride 512
    const float* Sg = (dir == 0 ? S1  : S2)  + b * 512;     // per-k normalizer
    const float* Bg = (dir == 0 ? U1  : U2)  + b * 131072;  // [k][n], stride 256
    const float* Pg = (dir == 0 ? P12 : P21) + b * 131072;  // [row][n], stride 256
    float* o = out + (dir == 0 ? 262144 : 0);

    __shared__ __align__(16) float As[32 * 68];
    __shared__ __align__(16) float Bs[32 * 40];
    const int tm4 = (t >> 4) << 2;
    const int tn2 = (t & 15) << 1;
    float a00=0,a01=0,a10=0,a11=0,a20=0,a21=0,a30=0,a31=0;

    for (int k0 = 0; k0 < 512; k0 += 32) {
        #pragma unroll
        for (int i = 0; i < 2; ++i) {          // A: 32 k x 64 rows, scale by rcp(S[k])
            int slot = i * 256 + t;
            int ak = slot >> 4, am4 = (slot & 15) << 2;
            float4 v = *(const float4*)(Ag + ((k0 + ak) << 9) + r0 + am4);
            float rs = __builtin_amdgcn_rcpf(Sg[k0 + ak]);
            v.x *= rs; v.y *= rs; v.z *= rs; v.w *= rs;
            *(float4*)(As + ak * 68 + am4) = v;
        }
        {
            int bk = t >> 3, bn4 = (t & 7) << 2;  // B: 32 k x 32 n
            *(float4*)(Bs + bk * 40 + bn4) =
                *(const float4*)(Bg + ((k0 + bk) << 8) + n0 + bn4);
        }
        __syncthreads();
        #pragma unroll 8
        for (int kk = 0; kk < 32; ++kk) {
            const float4 a  = *(const float4*)(As + kk * 68 + tm4);
            const float2 bv = *(const float2*)(Bs + kk * 40 + tn2);
            a00 += a.x*bv.x; a01 += a.x*bv.y;
            a10 += a.y*bv.x; a11 += a.y*bv.y;
            a20 += a.z*bv.x; a21 += a.z*bv.y;
            a30 += a.w*bv.x; a31 += a.w*bv.y;
        }
        __syncthreads();
    }

    float accs[4][2] = {{a00,a01},{a10,a11},{a20,a21},{a30,a31}};
    #pragma unroll
    for (int i = 0; i < 4; ++i) {
        int m = r0 + tm4 + i;
        float2 p = *(const float2*)(Pg + (m << 8) + n0 + tn2);
        float vx = accs[i][0] + p.x;
        float vy = accs[i][1] + p.y;
        float tx = 1.f - 2.f * __builtin_amdgcn_rcpf(
                       __builtin_amdgcn_exp2f(vx * TWO_LOG2E) + 1.f);
        float ty = 1.f - 2.f * __builtin_amdgcn_rcpf(
                       __builtin_amdgcn_exp2f(vy * TWO_LOG2E) + 1.f);
        *(float2*)(o + ((m << 1) + b) * 256 + n0 + tn2) = make_float2(tx, ty);
    }
}

// ---------------------------------------------------------------- launch
extern "C" void kernel_launch(void* const* d_in, const int* in_sizes, int n_in,
                              void* d_out, int out_size, void* d_ws, size_t ws_size,
                              hipStream_t stream)
{
    const float* ctx1 = (const float*)d_in[0];
    const float* ctx2 = (const float*)d_in[1];
    const float* m1   = (const float*)d_in[2];
    const float* m2   = (const float*)d_in[3];
    const float* Wh   = (const float*)d_in[4];
    const float* bh   = (const float*)d_in[5];
    const float* wo   = (const float*)d_in[6];
    const float* W12  = (const float*)d_in[7];
    const float* b12  = (const float*)d_in[8];
    const float* W21  = (const float*)d_in[9];
    const float* b21  = (const float*)d_in[10];
    float* out = (float*)d_out;
    float* ws  = (float*)d_ws;

    float* E1  = ws;                 // 262144
    float* E2  = E1  + 262144;
    float* P12 = E2  + 262144;
    float* U1  = P12 + 262144;
    float* P21 = U1  + 262144;
    float* U2  = P21 + 262144;
    float* p1  = U2  + 262144;       // 1024
    float* p2  = p1  + 1024;
    float* S1  = p2  + 1024;         // 1024
    float* S2  = S1  + 1024;
    float* ER  = S2  + 1024;         // 524288
    float* ECT = ER  + 524288;       // 524288

    hipLaunchKernelGGL(k_proj, dim3(16, 4, 6), dim3(256), 0, stream,
                       ctx1, ctx2, Wh, bh, W12, b12, W21, b21, m1, m2,
                       E1, E2, P12, U1, P21, U2, p1, p2, S1, S2);
    hipLaunchKernelGGL(k_aff, dim3(16, 16, 2), dim3(256), 0, stream,
                       E1, E2, wo, p1, p2, ER, ECT, S1, S2);
    hipLaunchKernelGGL(k_final, dim3(8, 8, 4), dim3(256), 0, stream,
                       ER, ECT, U1, U2, P12, P21, S1, S2, out);
}

// Round 7
// 140.963 us; speedup vs baseline: 2.5370x; 1.0604x over previous
//
#include <hip/hip_runtime.h>

// CoAttention, 3-kernel pipeline. R7: attack in-kernel latency (all kernels are
// grid-limited to 1-2 blocks/CU, so stalls are exposed).
//  k_proj : unchanged from R6 (control).
//  k_aff  : full-K LDS panels (65KB, stride 260 = bank-rotate-4), barriers 8->2,
//           single straight trans-bound compute loop.
//  k_final: 32x32 tiles -> grid 512 (2 blocks/CU), rcp(S) hoisted to LDS table.

#define NEGC (-1e12f)
#define TWO_LOG2E 2.8853900817779268f
#define LOG2E 1.4426950408889634f

// ---------------------------------------------------------------- k_proj
__global__ __launch_bounds__(256) void k_proj(
    const float* __restrict__ ctx1, const float* __restrict__ ctx2,
    const float* __restrict__ Wh, const float* __restrict__ bh,
    const float* __restrict__ W12, const float* __restrict__ b12,
    const float* __restrict__ W21, const float* __restrict__ b21,
    const float* __restrict__ mask1, const float* __restrict__ mask2,
    float* __restrict__ E1, float* __restrict__ E2,
    float* __restrict__ P12, float* __restrict__ U1,
    float* __restrict__ P21, float* __restrict__ U2,
    float* __restrict__ p1, float* __restrict__ p2,
    float* __restrict__ S1, float* __restrict__ S2)
{
    const int t  = threadIdx.x;
    const int g  = blockIdx.z;
    const int r0 = blockIdx.x * 64;       // rows = l*2+b in [0,1024)
    const int n0 = blockIdx.y * 64;       // N in [0,256)

    const float* A; const float* W; const float* bias; int expm; float* outp;
    switch (g) {
      case 0:  A=ctx1; W=Wh;        bias=bh;   expm=1; outp=E1;  break;
      case 1:  A=ctx2; W=Wh+65536;  bias=0;    expm=1; outp=E2;  break;
      case 2:  A=ctx2; W=W12;       bias=b12;  expm=0; outp=P12; break;
      case 3:  A=ctx1; W=W12+65536; bias=0;    expm=0; outp=U1;  break;
      case 4:  A=ctx1; W=W21;       bias=b21;  expm=0; outp=P21; break;
      default: A=ctx2; W=W21+65536; bias=0;    expm=0; outp=U2;  break;
    }

    if (g == 0 && blockIdx.x == 0 && blockIdx.y == 0) {
        for (int idx = t; idx < 1024; idx += 256) {
            int row = idx >> 1, b = idx & 1;
            p1[b * 512 + row] = __builtin_amdgcn_exp2f(LOG2E * (1.f - mask1[idx]) * NEGC);
            p2[b * 512 + row] = __builtin_amdgcn_exp2f(LOG2E * (1.f - mask2[idx]) * NEGC);
            S1[b * 512 + row] = 0.f;
            S2[b * 512 + row] = 0.f;
        }
    }

    __shared__ __align__(16) float As[32 * 68];   // [k][m]
    __shared__ __align__(16) float Bs[32 * 68];   // [k][n]
    const int tm4 = (t >> 4) << 2;
    const int tn4 = (t & 15) << 2;
    float acc[4][4] = {};

    for (int k0 = 0; k0 < 256; k0 += 32) {
        #pragma unroll
        for (int i = 0; i < 2; ++i) {            // A: 64 rows x 32 k -> transpose
            int slot = i * 256 + t;
            int r = slot >> 3, kq = (slot & 7) << 2;
            float4 v = *(const float4*)(A + (r0 + r) * 256 + k0 + kq);
            As[(kq + 0) * 68 + r] = v.x;
            As[(kq + 1) * 68 + r] = v.y;
            As[(kq + 2) * 68 + r] = v.z;
            As[(kq + 3) * 68 + r] = v.w;
        }
        #pragma unroll
        for (int i = 0; i < 2; ++i) {            // B: 32 k x 64 n straight
            int slot = i * 256 + t;
            int bk = slot >> 4, bn4 = (slot & 15) << 2;
            *(float4*)(Bs + bk * 68 + bn4) =
                *(const float4*)(W + (k0 + bk) * 256 + n0 + bn4);
        }
        __syncthreads();
        #pragma unroll 8
        for (int kk = 0; kk < 32; ++kk) {
            const float4 av = *(const float4*)(As + kk * 68 + tm4);
            const float4 bv = *(const float4*)(Bs + kk * 68 + tn4);
            acc[0][0] += av.x*bv.x; acc[0][1] += av.x*bv.y; acc[0][2] += av.x*bv.z; acc[0][3] += av.x*bv.w;
            acc[1][0] += av.y*bv.x; acc[1][1] += av.y*bv.y; acc[1][2] += av.y*bv.z; acc[1][3] += av.y*bv.w;
            acc[2][0] += av.z*bv.x; acc[2][1] += av.z*bv.y; acc[2][2] += av.z*bv.z; acc[2][3] += av.z*bv.w;
            acc[3][0] += av.w*bv.x; acc[3][1] += av.w*bv.y; acc[3][2] += av.w*bv.z; acc[3][3] += av.w*bv.w;
        }
        __syncthreads();
    }

    float4 bvz = make_float4(0.f, 0.f, 0.f, 0.f);
    if (bias) bvz = *(const float4*)(bias + n0 + tn4);
    #pragma unroll
    for (int i = 0; i < 4; ++i) {
        int row = r0 + tm4 + i;                  // row = l*2+b
        int orow = ((row & 1) << 9) + (row >> 1);
        float4 v;
        v.x = acc[i][0] + bvz.x; v.y = acc[i][1] + bvz.y;
        v.z = acc[i][2] + bvz.z; v.w = acc[i][3] + bvz.w;
        if (expm) {
            v.x = __builtin_amdgcn_exp2f(v.x * TWO_LOG2E);
            v.y = __builtin_amdgcn_exp2f(v.y * TWO_LOG2E);
            v.z = __builtin_amdgcn_exp2f(v.z * TWO_LOG2E);
            v.w = __builtin_amdgcn_exp2f(v.w * TWO_LOG2E);
        }
        *(float4*)(outp + orow * 256 + n0 + tn4) = v;
    }
}

// ---------------------------------------------------------------- k_aff
#define CELL(AV, QV, I, J) do {                                       \
    float r0_ = __builtin_amdgcn_rcpf(fmaf(AV.x, QV.x, 1.f));         \
    float r1_ = __builtin_amdgcn_rcpf(fmaf(AV.y, QV.y, 1.f));         \
    float r2_ = __builtin_amdgcn_rcpf(fmaf(AV.z, QV.z, 1.f));         \
    float r3_ = __builtin_amdgcn_rcpf(fmaf(AV.w, QV.w, 1.f));         \
    acc[I][J] = fmaf(w.x, r0_, fmaf(w.y, r1_, fmaf(w.z, r2_,          \
                fmaf(w.w, r3_, acc[I][J]))));                         \
} while (0)

__global__ __launch_bounds__(256) void k_aff(
    const float* __restrict__ E1g, const float* __restrict__ E2g,
    const float* __restrict__ wo,
    const float* __restrict__ p1g, const float* __restrict__ p2g,
    float* __restrict__ ER, float* __restrict__ ECT,
    float* __restrict__ S1, float* __restrict__ S2)
{
    const int t  = threadIdx.x;
    const int l0 = blockIdx.x * 32, m0 = blockIdx.y * 32, b = blockIdx.z;

    // full-K panels: stride 260 (260%32==4 -> bank rotates by 4 per row;
    // E2 16-row reads hit 16 distinct even-bank pairs = 2-way max = free)
    __shared__ __align__(16) float E1s[32 * 260];   // 33.3 KB
    __shared__ __align__(16) float E2s[32 * 260];   // 33.3 KB
    __shared__ __align__(16) float wos[256];
    __shared__ __align__(16) float affs[32 * 36];

    wos[t] = -2.f * wo[t];
    #pragma unroll
    for (int i = 0; i < 8; ++i) {                   // 32 rows x 256 k, both panels
        int slot = i * 256 + t;
        int r = slot >> 6, kq = (slot & 63) << 2;
        *(float4*)(E1s + r * 260 + kq) =
            *(const float4*)(E1g + (((b << 9) + l0 + r) << 8) + kq);
        *(float4*)(E2s + r * 260 + kq) =
            *(const float4*)(E2g + (((b << 9) + m0 + r) << 8) + kq);
    }
    __syncthreads();

    const int tl = t >> 4, tm = t & 15;             // cells: l in {tl,tl+16}, m in {tm,tm+16}
    const float* e1a = E1s + tl * 260;
    const float* e1b = E1s + (tl + 16) * 260;
    const float* e2a = E2s + tm * 260;
    const float* e2b = E2s + (tm + 16) * 260;
    float acc[2][2] = {};

    #pragma unroll 8
    for (int k0 = 0; k0 < 256; k0 += 4) {
        const float4 w  = *(const float4*)(wos + k0);
        const float4 a0 = *(const float4*)(e1a + k0);
        const float4 a1 = *(const float4*)(e1b + k0);
        const float4 q0 = *(const float4*)(e2a + k0);
        const float4 q1 = *(const float4*)(e2b + k0);
        CELL(a0, q0, 0, 0); CELL(a0, q1, 0, 1);
        CELL(a1, q0, 1, 0); CELL(a1, q1, 1, 1);
    }

    // E = exp(aff - SW); SW constant cancels in both softmaxes
    affs[tl * 36 + tm]               = __builtin_amdgcn_exp2f(acc[0][0] * LOG2E);
    affs[tl * 36 + tm + 16]          = __builtin_amdgcn_exp2f(acc[0][1] * LOG2E);
    affs[(tl + 16) * 36 + tm]        = __builtin_amdgcn_exp2f(acc[1][0] * LOG2E);
    affs[(tl + 16) * 36 + tm + 16]   = __builtin_amdgcn_exp2f(acc[1][1] * LOG2E);
    __syncthreads();

    const int r = t >> 3, c4 = (t & 7) << 2;
    // ER[l][m] = E * p2[m]; S1[l] += row sums
    {
        float4 e   = *(const float4*)(affs + r * 36 + c4);
        float4 p2v = *(const float4*)(p2g + (b << 9) + m0 + c4);
        float4 v = make_float4(e.x * p2v.x, e.y * p2v.y, e.z * p2v.z, e.w * p2v.w);
        *(float4*)(ER + (((b << 9) + l0 + r) << 9) + m0 + c4) = v;
        float s = (v.x + v.y) + (v.z + v.w);
        s += __shfl_xor(s, 1, 64);
        s += __shfl_xor(s, 2, 64);
        s += __shfl_xor(s, 4, 64);
        if ((t & 7) == 0) atomicAdd(S1 + (b << 9) + l0 + r, s);
    }
    // ECT[m][l] = E[l][m] * p1[l]; S2[m] += col sums
    {
        float4 p1v = *(const float4*)(p1g + (b << 9) + l0 + c4);
        float4 tv;
        tv.x = affs[(c4 + 0) * 36 + r] * p1v.x;
        tv.y = affs[(c4 + 1) * 36 + r] * p1v.y;
        tv.z = affs[(c4 + 2) * 36 + r] * p1v.z;
        tv.w = affs[(c4 + 3) * 36 + r] * p1v.w;
        *(float4*)(ECT + (((b << 9) + m0 + r) << 9) + l0 + c4) = tv;
        float s = (tv.x + tv.y) + (tv.z + tv.w);
        s += __shfl_xor(s, 1, 64);
        s += __shfl_xor(s, 2, 64);
        s += __shfl_xor(s, 4, 64);
        if ((t & 7) == 0) atomicAdd(S2 + (b << 9) + m0 + r, s);
    }
}

// --------------------------------------------------------------- k_final
__global__ __launch_bounds__(256) void k_final(
    const float* __restrict__ ER, const float* __restrict__ ECT,
    const float* __restrict__ U1, const float* __restrict__ U2,
    const float* __restrict__ P12, const float* __restrict__ P21,
    const float* __restrict__ S1, const float* __restrict__ S2,
    float* __restrict__ out)
{
    const int t   = threadIdx.x;
    const int r0  = blockIdx.x * 32, n0 = blockIdx.y * 32;
    const int dir = blockIdx.z >> 1, b = blockIdx.z & 1;
    const float* Ag = (dir == 0 ? ER  : ECT) + b * 262144;  // [k][row], stride 512
    const float* Sg = (dir == 0 ? S1  : S2)  + b * 512;     // per-k normalizer
    const float* Bg = (dir == 0 ? U1  : U2)  + b * 131072;  // [k][n], stride 256
    const float* Pg = (dir == 0 ? P12 : P21) + b * 131072;  // [row][n], stride 256
    float* o = out + (dir == 0 ? 262144 : 0);

    __shared__ __align__(16) float As[32 * 36];
    __shared__ __align__(16) float Bs[32 * 36];
    __shared__ __align__(16) float rs[512];
    const int tm_ = t >> 4, tn_ = t & 15;        // 2x2 cells: rows r0+2tm_+i, cols n0+2tn_+j

    for (int i = t; i < 512; i += 256)
        rs[i] = __builtin_amdgcn_rcpf(Sg[i]);
    __syncthreads();

    float acc[2][2] = {};
    const int ak = t >> 3, a4 = (t & 7) << 2;
    for (int k0 = 0; k0 < 512; k0 += 32) {
        {
            float4 v = *(const float4*)(Ag + ((k0 + ak) << 9) + r0 + a4);
            const float r_ = rs[k0 + ak];
            v.x *= r_; v.y *= r_; v.z *= r_; v.w *= r_;
            *(float4*)(As + ak * 36 + a4) = v;
            *(float4*)(Bs + ak * 36 + a4) =
                *(const float4*)(Bg + ((k0 + ak) << 8) + n0 + a4);
        }
        __syncthreads();
        #pragma unroll 8
        for (int kk = 0; kk < 32; ++kk) {
            const float2 av = *(const float2*)(As + kk * 36 + tm_ * 2);
            const float2 bv = *(const float2*)(Bs + kk * 36 + tn_ * 2);
            acc[0][0] += av.x * bv.x; acc[0][1] += av.x * bv.y;
            acc[1][0] += av.y * bv.x; acc[1][1] += av.y * bv.y;
        }
        __syncthreads();
    }

    #pragma unroll
    for (int i = 0; i < 2; ++i) {
        const int m = r0 + tm_ * 2 + i;
        float2 p = *(const float2*)(Pg + (m << 8) + n0 + tn_ * 2);
        float vx = acc[i][0] + p.x;
        float vy = acc[i][1] + p.y;
        float tx = 1.f - 2.f * __builtin_amdgcn_rcpf(
                       __builtin_amdgcn_exp2f(vx * TWO_LOG2E) + 1.f);
        float ty = 1.f - 2.f * __builtin_amdgcn_rcpf(
                       __builtin_amdgcn_exp2f(vy * TWO_LOG2E) + 1.f);
        *(float2*)(o + ((m << 1) + b) * 256 + n0 + tn_ * 2) = make_float2(tx, ty);
    }
}

// ---------------------------------------------------------------- launch
extern "C" void kernel_launch(void* const* d_in, const int* in_sizes, int n_in,
                              void* d_out, int out_size, void* d_ws, size_t ws_size,
                              hipStream_t stream)
{
    const float* ctx1 = (const float*)d_in[0];
    const float* ctx2 = (const float*)d_in[1];
    const float* m1   = (const float*)d_in[2];
    const float* m2   = (const float*)d_in[3];
    const float* Wh   = (const float*)d_in[4];
    const float* bh   = (const float*)d_in[5];
    const float* wo   = (const float*)d_in[6];
    const float* W12  = (const float*)d_in[7];
    const float* b12  = (const float*)d_in[8];
    const float* W21  = (const float*)d_in[9];
    const float* b21  = (const float*)d_in[10];
    float* out = (float*)d_out;
    float* ws  = (float*)d_ws;

    float* E1  = ws;                 // 262144
    float* E2  = E1  + 262144;
    float* P12 = E2  + 262144;
    float* U1  = P12 + 262144;
    float* P21 = U1  + 262144;
    float* U2  = P21 + 262144;
    float* p1  = U2  + 262144;       // 1024
    float* p2  = p1  + 1024;
    float* S1  = p2  + 1024;         // 1024
    float* S2  = S1  + 1024;
    float* ER  = S2  + 1024;         // 524288
    float* ECT = ER  + 524288;       // 524288

    hipLaunchKernelGGL(k_proj, dim3(16, 4, 6), dim3(256), 0, stream,
                       ctx1, ctx2, Wh, bh, W12, b12, W21, b21, m1, m2,
                       E1, E2, P12, U1, P21, U2, p1, p2, S1, S2);
    hipLaunchKernelGGL(k_aff, dim3(16, 16, 2), dim3(256), 0, stream,
                       E1, E2, wo, p1, p2, ER, ECT, S1, S2);
    hipLaunchKernelGGL(k_final, dim3(16, 8, 4), dim3(256), 0, stream,
                       ER, ECT, U1, U2, P12, P21, S1, S2, out);
}

// Round 8
// 133.882 us; speedup vs baseline: 2.6712x; 1.0529x over previous
//
#include <hip/hip_runtime.h>

// CoAttention, 3-kernel pipeline. R8:
//  k_proj : bf16 MFMA 16x16x32 (fp32 acc). fp32 GEMM was LDS-port-bound
//           (~85 flop/cy/CU); MFMA cuts LDS traffic 12x. W is transposed
//           into LDS (b16 scatter) so B-frags read k-contiguous.
//  k_aff  : retiled to 64x32 tiles, (4,2) cells/thread, K-chunks of 128 in
//           LDS: 0.875 b128/cell vs 1.25 -> ~9us, trans floor 6.8us.
//  k_final: unchanged from R7 (control).

#define NEGC (-1e12f)
#define TWO_LOG2E 2.8853900817779268f
#define LOG2E 1.4426950408889634f

typedef __attribute__((ext_vector_type(8))) short bf16x8;
typedef __attribute__((ext_vector_type(4))) float f32x4;

__device__ __forceinline__ short f2bf(float x)   // RNE truncation f32->bf16
{
    union { float f; unsigned u; } v; v.f = x;
    unsigned r = (v.u + 0x7FFFu + ((v.u >> 16) & 1u)) >> 16;
    return (short)r;
}

// ---------------------------------------------------------------- k_proj
// 6 GEMMs 1024x256 @ 256x256. Tile 64(M) x 64(N), 256 thr, wave w owns rows
// [w*16,w*16+16). K-chunks of 128 staged in LDS as bf16 (A: [m][k] stride 136,
// B^T: [n][k] stride 136), 4 MFMA k-steps of 32 per chunk.
__global__ __launch_bounds__(256) void k_proj(
    const float* __restrict__ ctx1, const float* __restrict__ ctx2,
    const float* __restrict__ Wh, const float* __restrict__ bh,
    const float* __restrict__ W12, const float* __restrict__ b12,
    const float* __restrict__ W21, const float* __restrict__ b21,
    const float* __restrict__ mask1, const float* __restrict__ mask2,
    float* __restrict__ E1, float* __restrict__ E2,
    float* __restrict__ P12, float* __restrict__ U1,
    float* __restrict__ P21, float* __restrict__ U2,
    float* __restrict__ p1, float* __restrict__ p2,
    float* __restrict__ S1, float* __restrict__ S2)
{
    const int t  = threadIdx.x;
    const int g  = blockIdx.z;
    const int r0 = blockIdx.x * 64;       // rows = l*2+b in [0,1024)
    const int n0 = blockIdx.y * 64;       // N in [0,256)

    const float* A; const float* W; const float* bias; int expm; float* outp;
    switch (g) {
      case 0:  A=ctx1; W=Wh;        bias=bh;   expm=1; outp=E1;  break;
      case 1:  A=ctx2; W=Wh+65536;  bias=0;    expm=1; outp=E2;  break;
      case 2:  A=ctx2; W=W12;       bias=b12;  expm=0; outp=P12; break;
      case 3:  A=ctx1; W=W12+65536; bias=0;    expm=0; outp=U1;  break;
      case 4:  A=ctx1; W=W21;       bias=b21;  expm=0; outp=P21; break;
      default: A=ctx2; W=W21+65536; bias=0;    expm=0; outp=U2;  break;
    }

    if (g == 0 && blockIdx.x == 0 && blockIdx.y == 0) {
        for (int idx = t; idx < 1024; idx += 256) {
            int row = idx >> 1, b = idx & 1;
            p1[b * 512 + row] = __builtin_amdgcn_exp2f(LOG2E * (1.f - mask1[idx]) * NEGC);
            p2[b * 512 + row] = __builtin_amdgcn_exp2f(LOG2E * (1.f - mask2[idx]) * NEGC);
            S1[b * 512 + row] = 0.f;
            S2[b * 512 + row] = 0.f;
        }
    }

    __shared__ __align__(16) short Abf[64 * 136];   // [m][k] bf16
    __shared__ __align__(16) short Bbf[64 * 136];   // [n][k] bf16 (W^T)

    const int w    = t >> 6;          // wave 0..3
    const int lane = t & 63;
    const int quad = lane >> 4;
    const int lr   = lane & 15;

    f32x4 acc[4] = {};                // 4 n-chunks of 16

    for (int kc = 0; kc < 256; kc += 128) {
        #pragma unroll
        for (int i = 0; i < 8; ++i) {                 // A: 64 rows x 128 k
            int slot = i * 256 + t;
            int r = slot >> 5, kq = (slot & 31) << 2;
            float4 v = *(const float4*)(A + (r0 + r) * 256 + kc + kq);
            short4 s; s.x = f2bf(v.x); s.y = f2bf(v.y); s.z = f2bf(v.z); s.w = f2bf(v.w);
            *(short4*)(Abf + r * 136 + kq) = s;
        }
        #pragma unroll
        for (int i = 0; i < 8; ++i) {                 // B: 128 k x 64 n -> B^T
            int slot = i * 256 + t;
            int bk = slot >> 4, bn4 = (slot & 15) << 2;
            float4 v = *(const float4*)(W + (kc + bk) * 256 + n0 + bn4);
            Bbf[(bn4 + 0) * 136 + bk] = f2bf(v.x);
            Bbf[(bn4 + 1) * 136 + bk] = f2bf(v.y);
            Bbf[(bn4 + 2) * 136 + bk] = f2bf(v.z);
            Bbf[(bn4 + 3) * 136 + bk] = f2bf(v.w);
        }
        __syncthreads();
        #pragma unroll
        for (int s = 0; s < 4; ++s) {                 // 4 MFMA k-steps of 32
            const int kb = s * 32 + quad * 8;
            bf16x8 a = *(const bf16x8*)(Abf + (w * 16 + lr) * 136 + kb);
            #pragma unroll
            for (int nc = 0; nc < 4; ++nc) {
                bf16x8 b = *(const bf16x8*)(Bbf + (nc * 16 + lr) * 136 + kb);
                acc[nc] = __builtin_amdgcn_mfma_f32_16x16x32_bf16(a, b, acc[nc], 0, 0, 0);
            }
        }
        __syncthreads();
    }

    // epilogue: D[row=(quad*4+reg)][col=lane&15] per 16x16 tile
    #pragma unroll
    for (int nc = 0; nc < 4; ++nc) {
        const int col = n0 + nc * 16 + lr;
        const float bv = bias ? bias[col] : 0.f;
        #pragma unroll
        for (int reg = 0; reg < 4; ++reg) {
            int row  = r0 + w * 16 + quad * 4 + reg;   // = l*2+b
            int orow = ((row & 1) << 9) + (row >> 1);
            float v = acc[nc][reg] + bv;
            if (expm) v = __builtin_amdgcn_exp2f(v * TWO_LOG2E);
            outp[orow * 256 + col] = v;
        }
    }
}

// ---------------------------------------------------------------- k_aff
#define CELL2(AV, QV, ACC) do {                                       \
    float r0_ = __builtin_amdgcn_rcpf(fmaf(AV.x, QV.x, 1.f));         \
    float r1_ = __builtin_amdgcn_rcpf(fmaf(AV.y, QV.y, 1.f));         \
    float r2_ = __builtin_amdgcn_rcpf(fmaf(AV.z, QV.z, 1.f));         \
    float r3_ = __builtin_amdgcn_rcpf(fmaf(AV.w, QV.w, 1.f));         \
    ACC = fmaf(w.x, r0_, fmaf(w.y, r1_, fmaf(w.z, r2_,                \
          fmaf(w.w, r3_, ACC))));                                     \
} while (0)

__global__ __launch_bounds__(256) void k_aff(
    const float* __restrict__ E1g, const float* __restrict__ E2g,
    const float* __restrict__ wo,
    const float* __restrict__ p1g, const float* __restrict__ p2g,
    float* __restrict__ ER, float* __restrict__ ECT,
    float* __restrict__ S1, float* __restrict__ S2)
{
    const int t  = threadIdx.x;
    const int l0 = blockIdx.x * 64, m0 = blockIdx.y * 32, b = blockIdx.z;

    __shared__ __align__(16) float E1s[64 * 132];   // 33.8 KB
    __shared__ __align__(16) float E2s[32 * 132];   // 16.9 KB
    __shared__ __align__(16) float affs[64 * 36];   // 9.2 KB
    __shared__ __align__(16) float wos[256];

    wos[t] = -2.f * wo[t];
    const int tl = t >> 4, tm = t & 15;   // cells: l = tl+16i (i<4), m = tm, tm+16
    float acc[4][2] = {};

    for (int kc = 0; kc < 256; kc += 128) {
        #pragma unroll
        for (int i = 0; i < 8; ++i) {               // E1: 64 rows x 128 k
            int slot = i * 256 + t;
            int r = slot >> 5, kq = (slot & 31) << 2;
            *(float4*)(E1s + r * 132 + kq) =
                *(const float4*)(E1g + (((b << 9) + l0 + r) << 8) + kc + kq);
        }
        #pragma unroll
        for (int i = 0; i < 4; ++i) {               // E2: 32 rows x 128 k
            int slot = i * 256 + t;
            int r = slot >> 5, kq = (slot & 31) << 2;
            *(float4*)(E2s + r * 132 + kq) =
                *(const float4*)(E2g + (((b << 9) + m0 + r) << 8) + kc + kq);
        }
        __syncthreads();
        #pragma unroll 4
        for (int k0 = 0; k0 < 128; k0 += 4) {
            const float4 w  = *(const float4*)(wos + kc + k0);
            const float4 q0 = *(const float4*)(E2s + tm * 132 + k0);
            const float4 q1 = *(const float4*)(E2s + (tm + 16) * 132 + k0);
            #pragma unroll
            for (int i = 0; i < 4; ++i) {
                const float4 a = *(const float4*)(E1s + (tl + 16 * i) * 132 + k0);
                CELL2(a, q0, acc[i][0]);
                CELL2(a, q1, acc[i][1]);
            }
        }
        __syncthreads();
    }

    #pragma unroll
    for (int i = 0; i < 4; ++i) {
        affs[(tl + 16 * i) * 36 + tm]      = __builtin_amdgcn_exp2f(acc[i][0] * LOG2E);
        affs[(tl + 16 * i) * 36 + tm + 16] = __builtin_amdgcn_exp2f(acc[i][1] * LOG2E);
    }
    __syncthreads();

    // ER[l][m] = E * p2[m]; S1[l] += row sums   (64 rows x 32 cols)
    #pragma unroll
    for (int i = 0; i < 2; ++i) {
        int slot = i * 256 + t;
        int r = slot >> 3, c4 = (slot & 7) << 2;
        float4 e   = *(const float4*)(affs + r * 36 + c4);
        float4 p2v = *(const float4*)(p2g + (b << 9) + m0 + c4);
        float4 v = make_float4(e.x * p2v.x, e.y * p2v.y, e.z * p2v.z, e.w * p2v.w);
        *(float4*)(ER + (((b << 9) + l0 + r) << 9) + m0 + c4) = v;
        float s = (v.x + v.y) + (v.z + v.w);
        s += __shfl_xor(s, 1, 64);
        s += __shfl_xor(s, 2, 64);
        s += __shfl_xor(s, 4, 64);
        if ((t & 7) == 0) atomicAdd(S1 + (b << 9) + l0 + r, s);
    }
    // ECT[m][l] = E[l][m] * p1[l]; S2[m] += col sums  (32 rows x 64 cols)
    #pragma unroll
    for (int i = 0; i < 2; ++i) {
        int slot = i * 256 + t;
        int r = slot >> 4, c4 = (slot & 15) << 2;
        float4 p1v = *(const float4*)(p1g + (b << 9) + l0 + c4);
        float4 tv;
        tv.x = affs[(c4 + 0) * 36 + r] * p1v.x;
        tv.y = affs[(c4 + 1) * 36 + r] * p1v.y;
        tv.z = affs[(c4 + 2) * 36 + r] * p1v.z;
        tv.w = affs[(c4 + 3) * 36 + r] * p1v.w;
        *(float4*)(ECT + (((b << 9) + m0 + r) << 9) + l0 + c4) = tv;
        float s = (tv.x + tv.y) + (tv.z + tv.w);
        s += __shfl_xor(s, 1, 64);
        s += __shfl_xor(s, 2, 64);
        s += __shfl_xor(s, 4, 64);
        s += __shfl_xor(s, 8, 64);
        if ((t & 15) == 0) atomicAdd(S2 + (b << 9) + m0 + r, s);
    }
}

// --------------------------------------------------------------- k_final
__global__ __launch_bounds__(256) void k_final(
    const float* __restrict__ ER, const float* __restrict__ ECT,
    const float* __restrict__ U1, const float* __restrict__ U2,
    const float* __restrict__ P12, const float* __restrict__ P21,
    const float* __restrict__ S1, const float* __restrict__ S2,
    float* __restrict__ out)
{
    const int t   = threadIdx.x;
    const int r0  = blockIdx.x * 32, n0 = blockIdx.y * 32;
    const int dir = blockIdx.z >> 1, b = blockIdx.z & 1;
    const float* Ag = (dir == 0 ? ER  : ECT) + b * 262144;  // [k][row], stride 512
    const float* Sg = (dir == 0 ? S1  : S2)  + b * 512;     // per-k normalizer
    const float* Bg = (dir == 0 ? U1  : U2)  + b * 131072;  // [k][n], stride 256
    const float* Pg = (dir == 0 ? P12 : P21) + b * 131072;  // [row][n], stride 256
    float* o = out + (dir == 0 ? 262144 : 0);

    __shared__ __align__(16) float As[32 * 36];
    __shared__ __align__(16) float Bs[32 * 36];
    __shared__ __align__(16) float rs[512];
    const int tm_ = t >> 4, tn_ = t & 15;

    for (int i = t; i < 512; i += 256)
        rs[i] = __builtin_amdgcn_rcpf(Sg[i]);
    __syncthreads();

    float acc[2][2] = {};
    const int ak = t >> 3, a4 = (t & 7) << 2;
    for (int k0 = 0; k0 < 512; k0 += 32) {
        {
            float4 v = *(const float4*)(Ag + ((k0 + ak) << 9) + r0 + a4);
            const float r_ = rs[k0 + ak];
            v.x *= r_; v.y *= r_; v.z *= r_; v.w *= r_;
            *(float4*)(As + ak * 36 + a4) = v;
            *(float4*)(Bs + ak * 36 + a4) =
                *(const float4*)(Bg + ((k0 + ak) << 8) + n0 + a4);
        }
        __syncthreads();
        #pragma unroll 8
        for (int kk = 0; kk < 32; ++kk) {
            const float2 av = *(const float2*)(As + kk * 36 + tm_ * 2);
            const float2 bv = *(const float2*)(Bs + kk * 36 + tn_ * 2);
            acc[0][0] += av.x * bv.x; acc[0][1] += av.x * bv.y;
            acc[1][0] += av.y * bv.x; acc[1][1] += av.y * bv.y;
        }
        __syncthreads();
    }

    #pragma unroll
    for (int i = 0; i < 2; ++i) {
        const int m = r0 + tm_ * 2 + i;
        float2 p = *(const float2*)(Pg + (m << 8) + n0 + tn_ * 2);
        float vx = acc[i][0] + p.x;
        float vy = acc[i][1] + p.y;
        float tx = 1.f - 2.f * __builtin_amdgcn_rcpf(
                       __builtin_amdgcn_exp2f(vx * TWO_LOG2E) + 1.f);
        float ty = 1.f - 2.f * __builtin_amdgcn_rcpf(
                       __builtin_amdgcn_exp2f(vy * TWO_LOG2E) + 1.f);
        *(float2*)(o + ((m << 1) + b) * 256 + n0 + tn_ * 2) = make_float2(tx, ty);
    }
}

// ---------------------------------------------------------------- launch
extern "C" void kernel_launch(void* const* d_in, const int* in_sizes, int n_in,
                              void* d_out, int out_size, void* d_ws, size_t ws_size,
                              hipStream_t stream)
{
    const float* ctx1 = (const float*)d_in[0];
    const float* ctx2 = (const float*)d_in[1];
    const float* m1   = (const float*)d_in[2];
    const float* m2   = (const float*)d_in[3];
    const float* Wh   = (const float*)d_in[4];
    const float* bh   = (const float*)d_in[5];
    const float* wo   = (const float*)d_in[6];
    const float* W12  = (const float*)d_in[7];
    const float* b12  = (const float*)d_in[8];
    const float* W21  = (const float*)d_in[9];
    const float* b21  = (const float*)d_in[10];
    float* out = (float*)d_out;
    float* ws  = (float*)d_ws;

    float* E1  = ws;                 // 262144
    float* E2  = E1  + 262144;
    float* P12 = E2  + 262144;
    float* U1  = P12 + 262144;
    float* P21 = U1  + 262144;
    float* U2  = P21 + 262144;
    float* p1  = U2  + 262144;       // 1024
    float* p2  = p1  + 1024;
    float* S1  = p2  + 1024;         // 1024
    float* S2  = S1  + 1024;
    float* ER  = S2  + 1024;         // 524288
    float* ECT = ER  + 524288;       // 524288

    hipLaunchKernelGGL(k_proj, dim3(16, 4, 6), dim3(256), 0, stream,
                       ctx1, ctx2, Wh, bh, W12, b12, W21, b21, m1, m2,
                       E1, E2, P12, U1, P21, U2, p1, p2, S1, S2);
    hipLaunchKernelGGL(k_aff, dim3(8, 16, 2), dim3(256), 0, stream,
                       E1, E2, wo, p1, p2, ER, ECT, S1, S2);
    hipLaunchKernelGGL(k_final, dim3(16, 8, 4), dim3(256), 0, stream,
                       ER, ECT, U1, U2, P12, P21, S1, S2, out);
}

// Round 9
// 120.849 us; speedup vs baseline: 2.9593x; 1.1078x over previous
//
#include <hip/hip_runtime.h>

// CoAttention, 3-kernel pipeline. R9:
//  k_proj : unchanged (bf16 MFMA, R8).
//  k_aff  : same compute; output layout swap (cost-neutral): EN[l][m]=E*p1[l]
//           (natural), ET[m][l]=E^T*p2[m] (transposed) -> BOTH k_final A-mats
//           are [row][k] k-contiguous. S1=rowsum(E*p2), S2=colsum(E*p1) as before.
//  k_final: bf16 MFMA 16x16x32. A stages contiguous (scale rs[k] in-flight),
//           only B (U) needs b16 scatter transpose. Was ds_read_b64-bound
//           (~8k LDS instr/CU ~ 20us); now ~10x fewer LDS instrs.

#define NEGC (-1e12f)
#define TWO_LOG2E 2.8853900817779268f
#define LOG2E 1.4426950408889634f

typedef __attribute__((ext_vector_type(8))) short bf16x8;
typedef __attribute__((ext_vector_type(4))) float f32x4;

__device__ __forceinline__ short f2bf(float x)   // RNE f32->bf16
{
    union { float f; unsigned u; } v; v.f = x;
    unsigned r = (v.u + 0x7FFFu + ((v.u >> 16) & 1u)) >> 16;
    return (short)r;
}

// ---------------------------------------------------------------- k_proj
__global__ __launch_bounds__(256) void k_proj(
    const float* __restrict__ ctx1, const float* __restrict__ ctx2,
    const float* __restrict__ Wh, const float* __restrict__ bh,
    const float* __restrict__ W12, const float* __restrict__ b12,
    const float* __restrict__ W21, const float* __restrict__ b21,
    const float* __restrict__ mask1, const float* __restrict__ mask2,
    float* __restrict__ E1, float* __restrict__ E2,
    float* __restrict__ P12, float* __restrict__ U1,
    float* __restrict__ P21, float* __restrict__ U2,
    float* __restrict__ p1, float* __restrict__ p2,
    float* __restrict__ S1, float* __restrict__ S2)
{
    const int t  = threadIdx.x;
    const int g  = blockIdx.z;
    const int r0 = blockIdx.x * 64;       // rows = l*2+b in [0,1024)
    const int n0 = blockIdx.y * 64;       // N in [0,256)

    const float* A; const float* W; const float* bias; int expm; float* outp;
    switch (g) {
      case 0:  A=ctx1; W=Wh;        bias=bh;   expm=1; outp=E1;  break;
      case 1:  A=ctx2; W=Wh+65536;  bias=0;    expm=1; outp=E2;  break;
      case 2:  A=ctx2; W=W12;       bias=b12;  expm=0; outp=P12; break;
      case 3:  A=ctx1; W=W12+65536; bias=0;    expm=0; outp=U1;  break;
      case 4:  A=ctx1; W=W21;       bias=b21;  expm=0; outp=P21; break;
      default: A=ctx2; W=W21+65536; bias=0;    expm=0; outp=U2;  break;
    }

    if (g == 0 && blockIdx.x == 0 && blockIdx.y == 0) {
        for (int idx = t; idx < 1024; idx += 256) {
            int row = idx >> 1, b = idx & 1;
            p1[b * 512 + row] = __builtin_amdgcn_exp2f(LOG2E * (1.f - mask1[idx]) * NEGC);
            p2[b * 512 + row] = __builtin_amdgcn_exp2f(LOG2E * (1.f - mask2[idx]) * NEGC);
            S1[b * 512 + row] = 0.f;
            S2[b * 512 + row] = 0.f;
        }
    }

    __shared__ __align__(16) short Abf[64 * 136];   // [m][k] bf16
    __shared__ __align__(16) short Bbf[64 * 136];   // [n][k] bf16 (W^T)

    const int w    = t >> 6;
    const int lane = t & 63;
    const int quad = lane >> 4;
    const int lr   = lane & 15;

    f32x4 acc[4] = {};

    for (int kc = 0; kc < 256; kc += 128) {
        #pragma unroll
        for (int i = 0; i < 8; ++i) {                 // A: 64 rows x 128 k
            int slot = i * 256 + t;
            int r = slot >> 5, kq = (slot & 31) << 2;
            float4 v = *(const float4*)(A + (r0 + r) * 256 + kc + kq);
            short4 s; s.x = f2bf(v.x); s.y = f2bf(v.y); s.z = f2bf(v.z); s.w = f2bf(v.w);
            *(short4*)(Abf + r * 136 + kq) = s;
        }
        #pragma unroll
        for (int i = 0; i < 8; ++i) {                 // B: 128 k x 64 n -> B^T
            int slot = i * 256 + t;
            int bk = slot >> 4, bn4 = (slot & 15) << 2;
            float4 v = *(const float4*)(W + (kc + bk) * 256 + n0 + bn4);
            Bbf[(bn4 + 0) * 136 + bk] = f2bf(v.x);
            Bbf[(bn4 + 1) * 136 + bk] = f2bf(v.y);
            Bbf[(bn4 + 2) * 136 + bk] = f2bf(v.z);
            Bbf[(bn4 + 3) * 136 + bk] = f2bf(v.w);
        }
        __syncthreads();
        #pragma unroll
        for (int s = 0; s < 4; ++s) {
            const int kb = s * 32 + quad * 8;
            bf16x8 a = *(const bf16x8*)(Abf + (w * 16 + lr) * 136 + kb);
            #pragma unroll
            for (int nc = 0; nc < 4; ++nc) {
                bf16x8 b = *(const bf16x8*)(Bbf + (nc * 16 + lr) * 136 + kb);
                acc[nc] = __builtin_amdgcn_mfma_f32_16x16x32_bf16(a, b, acc[nc], 0, 0, 0);
            }
        }
        __syncthreads();
    }

    #pragma unroll
    for (int nc = 0; nc < 4; ++nc) {
        const int col = n0 + nc * 16 + lr;
        const float bv = bias ? bias[col] : 0.f;
        #pragma unroll
        for (int reg = 0; reg < 4; ++reg) {
            int row  = r0 + w * 16 + quad * 4 + reg;   // = l*2+b
            int orow = ((row & 1) << 9) + (row >> 1);
            float v = acc[nc][reg] + bv;
            if (expm) v = __builtin_amdgcn_exp2f(v * TWO_LOG2E);
            outp[orow * 256 + col] = v;
        }
    }
}

// ---------------------------------------------------------------- k_aff
#define CELL2(AV, QV, ACC) do {                                       \
    float r0_ = __builtin_amdgcn_rcpf(fmaf(AV.x, QV.x, 1.f));         \
    float r1_ = __builtin_amdgcn_rcpf(fmaf(AV.y, QV.y, 1.f));         \
    float r2_ = __builtin_amdgcn_rcpf(fmaf(AV.z, QV.z, 1.f));         \
    float r3_ = __builtin_amdgcn_rcpf(fmaf(AV.w, QV.w, 1.f));         \
    ACC = fmaf(w.x, r0_, fmaf(w.y, r1_, fmaf(w.z, r2_,                \
          fmaf(w.w, r3_, ACC))));                                     \
} while (0)

__global__ __launch_bounds__(256) void k_aff(
    const float* __restrict__ E1g, const float* __restrict__ E2g,
    const float* __restrict__ wo,
    const float* __restrict__ p1g, const float* __restrict__ p2g,
    float* __restrict__ EN, float* __restrict__ ET,
    float* __restrict__ S1, float* __restrict__ S2)
{
    const int t  = threadIdx.x;
    const int l0 = blockIdx.x * 64, m0 = blockIdx.y * 32, b = blockIdx.z;

    __shared__ __align__(16) float E1s[64 * 132];
    __shared__ __align__(16) float E2s[32 * 132];
    __shared__ __align__(16) float affs[64 * 36];
    __shared__ __align__(16) float wos[256];

    wos[t] = -2.f * wo[t];
    const int tl = t >> 4, tm = t & 15;   // cells: l = tl+16i (i<4), m = tm, tm+16
    float acc[4][2] = {};

    for (int kc = 0; kc < 256; kc += 128) {
        #pragma unroll
        for (int i = 0; i < 8; ++i) {
            int slot = i * 256 + t;
            int r = slot >> 5, kq = (slot & 31) << 2;
            *(float4*)(E1s + r * 132 + kq) =
                *(const float4*)(E1g + (((b << 9) + l0 + r) << 8) + kc + kq);
        }
        #pragma unroll
        for (int i = 0; i < 4; ++i) {
            int slot = i * 256 + t;
            int r = slot >> 5, kq = (slot & 31) << 2;
            *(float4*)(E2s + r * 132 + kq) =
                *(const float4*)(E2g + (((b << 9) + m0 + r) << 8) + kc + kq);
        }
        __syncthreads();
        #pragma unroll 4
        for (int k0 = 0; k0 < 128; k0 += 4) {
            const float4 w  = *(const float4*)(wos + kc + k0);
            const float4 q0 = *(const float4*)(E2s + tm * 132 + k0);
            const float4 q1 = *(const float4*)(E2s + (tm + 16) * 132 + k0);
            #pragma unroll
            for (int i = 0; i < 4; ++i) {
                const float4 a = *(const float4*)(E1s + (tl + 16 * i) * 132 + k0);
                CELL2(a, q0, acc[i][0]);
                CELL2(a, q1, acc[i][1]);
            }
        }
        __syncthreads();
    }

    #pragma unroll
    for (int i = 0; i < 4; ++i) {
        affs[(tl + 16 * i) * 36 + tm]      = __builtin_amdgcn_exp2f(acc[i][0] * LOG2E);
        affs[(tl + 16 * i) * 36 + tm + 16] = __builtin_amdgcn_exp2f(acc[i][1] * LOG2E);
    }
    __syncthreads();

    // natural pass (64 l-rows x 32 m-cols): EN[l][m]=E*p1[l]; S1[l]+=sum_m E*p2[m]
    #pragma unroll
    for (int i = 0; i < 2; ++i) {
        int slot = i * 256 + t;
        int r = slot >> 3, c4 = (slot & 7) << 2;
        float4 e   = *(const float4*)(affs + r * 36 + c4);
        const float p1r = p1g[(b << 9) + l0 + r];
        float4 vn = make_float4(e.x * p1r, e.y * p1r, e.z * p1r, e.w * p1r);
        *(float4*)(EN + (((b << 9) + l0 + r) << 9) + m0 + c4) = vn;
        float4 p2v = *(const float4*)(p2g + (b << 9) + m0 + c4);
        float s = (e.x * p2v.x + e.y * p2v.y) + (e.z * p2v.z + e.w * p2v.w);
        s += __shfl_xor(s, 1, 64);
        s += __shfl_xor(s, 2, 64);
        s += __shfl_xor(s, 4, 64);
        if ((t & 7) == 0) atomicAdd(S1 + (b << 9) + l0 + r, s);
    }
    // transposed pass (32 m-rows x 64 l-cols): ET[m][l]=E^T*p2[m]; S2[m]+=sum_l E*p1[l]
    #pragma unroll
    for (int i = 0; i < 2; ++i) {
        int slot = i * 256 + t;
        int r = slot >> 4, c4 = (slot & 15) << 2;
        float4 te;
        te.x = affs[(c4 + 0) * 36 + r];
        te.y = affs[(c4 + 1) * 36 + r];
        te.z = affs[(c4 + 2) * 36 + r];
        te.w = affs[(c4 + 3) * 36 + r];
        const float p2r = p2g[(b << 9) + m0 + r];
        float4 vt = make_float4(te.x * p2r, te.y * p2r, te.z * p2r, te.w * p2r);
        *(float4*)(ET + (((b << 9) + m0 + r) << 9) + l0 + c4) = vt;
        float4 p1v = *(const float4*)(p1g + (b << 9) + l0 + c4);
        float s = (te.x * p1v.x + te.y * p1v.y) + (te.z * p1v.z + te.w * p1v.w);
        s += __shfl_xor(s, 1, 64);
        s += __shfl_xor(s, 2, 64);
        s += __shfl_xor(s, 4, 64);
        s += __shfl_xor(s, 8, 64);
        if ((t & 15) == 0) atomicAdd(S2 + (b << 9) + m0 + r, s);
    }
}

// --------------------------------------------------------------- k_final
// out[row][n] = tanh(P[row][n] + sum_k A[row][k]*rs[k]*U[k][n]),
// A = ET (dir0, row=m, k=l) or EN (dir1, row=l, k=m), both [row][k] stride 512.
__global__ __launch_bounds__(256) void k_final(
    const float* __restrict__ EN, const float* __restrict__ ET,
    const float* __restrict__ U1, const float* __restrict__ U2,
    const float* __restrict__ P12, const float* __restrict__ P21,
    const float* __restrict__ S1, const float* __restrict__ S2,
    float* __restrict__ out)
{
    const int t   = threadIdx.x;
    const int r0  = blockIdx.x * 32, n0 = blockIdx.y * 32;
    const int dir = blockIdx.z >> 1, b = blockIdx.z & 1;
    const float* Ag = (dir == 0 ? ET  : EN)  + b * 262144;  // [row][k], stride 512
    const float* Sg = (dir == 0 ? S1  : S2)  + b * 512;
    const float* Bg = (dir == 0 ? U1  : U2)  + b * 131072;  // [k][n], stride 256
    const float* Pg = (dir == 0 ? P12 : P21) + b * 131072;  // [row][n], stride 256
    float* o = out + (dir == 0 ? 262144 : 0);

    __shared__ __align__(16) short Abf[32 * 72];    // [row][k] bf16, rs folded
    __shared__ __align__(16) short Bbf[32 * 72];    // [n][k] bf16 (U^T)
    __shared__ __align__(16) float rs[512];

    for (int i = t; i < 512; i += 256)
        rs[i] = __builtin_amdgcn_rcpf(Sg[i]);
    __syncthreads();

    const int w    = t >> 6;                        // wave -> 16x16 subtile
    const int lane = t & 63;
    const int quad = lane >> 4;
    const int lr   = lane & 15;
    const int wr   = (w >> 1) << 4, wc = (w & 1) << 4;
    f32x4 acc = {};

    for (int kc = 0; kc < 512; kc += 64) {
        #pragma unroll
        for (int i = 0; i < 2; ++i) {               // A: 32 rows x 64 k, rs-scaled
            int slot = i * 256 + t;
            int r = slot >> 4, kq = (slot & 15) << 2;
            float4 v = *(const float4*)(Ag + ((r0 + r) << 9) + kc + kq);
            const float* rp = rs + kc + kq;
            short4 s;
            s.x = f2bf(v.x * rp[0]); s.y = f2bf(v.y * rp[1]);
            s.z = f2bf(v.z * rp[2]); s.w = f2bf(v.w * rp[3]);
            *(short4*)(Abf + r * 72 + kq) = s;
        }
        #pragma unroll
        for (int i = 0; i < 2; ++i) {               // B: 64 k x 32 n -> [n][k]
            int slot = i * 256 + t;
            int bk = slot >> 3, bn4 = (slot & 7) << 2;
            float4 v = *(const float4*)(Bg + ((kc + bk) << 8) + n0 + bn4);
            Bbf[(bn4 + 0) * 72 + bk] = f2bf(v.x);
            Bbf[(bn4 + 1) * 72 + bk] = f2bf(v.y);
            Bbf[(bn4 + 2) * 72 + bk] = f2bf(v.z);
            Bbf[(bn4 + 3) * 72 + bk] = f2bf(v.w);
        }
        __syncthreads();
        #pragma unroll
        for (int s = 0; s < 2; ++s) {               // 2 MFMA k-steps of 32
            const int kb = s * 32 + quad * 8;
            bf16x8 a = *(const bf16x8*)(Abf + (wr + lr) * 72 + kb);
            bf16x8 bb = *(const bf16x8*)(Bbf + (wc + lr) * 72 + kb);
            acc = __builtin_amdgcn_mfma_f32_16x16x32_bf16(a, bb, acc, 0, 0, 0);
        }
        __syncthreads();
    }

    // D[row=quad*4+reg][col=lr]; add P, tanh, store
    const int col = n0 + wc + lr;
    #pragma unroll
    for (int reg = 0; reg < 4; ++reg) {
        const int m = r0 + wr + quad * 4 + reg;
        float v = acc[reg] + Pg[(m << 8) + col];
        float tv = 1.f - 2.f * __builtin_amdgcn_rcpf(
                       __builtin_amdgcn_exp2f(v * TWO_LOG2E) + 1.f);
        o[((m << 1) + b) * 256 + col] = tv;
    }
}

// ---------------------------------------------------------------- launch
extern "C" void kernel_launch(void* const* d_in, const int* in_sizes, int n_in,
                              void* d_out, int out_size, void* d_ws, size_t ws_size,
                              hipStream_t stream)
{
    const float* ctx1 = (const float*)d_in[0];
    const float* ctx2 = (const float*)d_in[1];
    const float* m1   = (const float*)d_in[2];
    const float* m2   = (const float*)d_in[3];
    const float* Wh   = (const float*)d_in[4];
    const float* bh   = (const float*)d_in[5];
    const float* wo   = (const float*)d_in[6];
    const float* W12  = (const float*)d_in[7];
    const float* b12  = (const float*)d_in[8];
    const float* W21  = (const float*)d_in[9];
    const float* b21  = (const float*)d_in[10];
    float* out = (float*)d_out;
    float* ws  = (float*)d_ws;

    float* E1  = ws;                 // 262144
    float* E2  = E1  + 262144;
    float* P12 = E2  + 262144;
    float* U1  = P12 + 262144;
    float* P21 = U1  + 262144;
    float* U2  = P21 + 262144;
    float* p1  = U2  + 262144;       // 1024
    float* p2  = p1  + 1024;
    float* S1  = p2  + 1024;         // 1024
    float* S2  = S1  + 1024;
    float* EN  = S2  + 1024;         // 524288
    float* ET  = EN  + 524288;       // 524288

    hipLaunchKernelGGL(k_proj, dim3(16, 4, 6), dim3(256), 0, stream,
                       ctx1, ctx2, Wh, bh, W12, b12, W21, b21, m1, m2,
                       E1, E2, P12, U1, P21, U2, p1, p2, S1, S2);
    hipLaunchKernelGGL(k_aff, dim3(8, 16, 2), dim3(256), 0, stream,
                       E1, E2, wo, p1, p2, EN, ET, S1, S2);
    hipLaunchKernelGGL(k_final, dim3(16, 8, 4), dim3(256), 0, stream,
                       EN, ET, U1, U2, P12, P21, S1, S2, out);
}